// Round 21
// baseline (1088.516 us; speedup 1.0000x reference)
//
#include <hip/hip_runtime.h>
#include <cstddef>
#include <cstdint>

constexpr int NB = 256;
constexpr int NT = 512;
constexpr int NV = 32;

typedef _Float16 h2_t __attribute__((ext_vector_type(2)));
typedef _Float16 f16x8 __attribute__((ext_vector_type(8)));
typedef float f32x4 __attribute__((ext_vector_type(4)));

__device__ __forceinline__ float sigmoidf_(float x){ return 1.0f/(1.0f+__expf(-x)); }
__device__ __forceinline__ float tanhf_(float x){ return 1.0f - 2.0f/(__expf(2.0f*x)+1.0f); }

__device__ __forceinline__ uint32_t pack2u_(float a, float b){
  h2_t r; r.x=(_Float16)a; r.y=(_Float16)b; return __builtin_bit_cast(uint32_t, r);
}
__device__ __forceinline__ float dot2u_(uint32_t u, uint32_t w, float c){
#if __has_builtin(__builtin_amdgcn_fdot2)
  return __builtin_amdgcn_fdot2(__builtin_bit_cast(h2_t,u), __builtin_bit_cast(h2_t,w), c, false);
#else
  h2_t a=__builtin_bit_cast(h2_t,u), b=__builtin_bit_cast(h2_t,w);
  return c + (float)a.x*(float)b.x + (float)a.y*(float)b.y;
#endif
}
__device__ __forceinline__ float h2f_(unsigned short u){
  _Float16 hv = __builtin_bit_cast(_Float16, u); return (float)hv;
}
__device__ __forceinline__ unsigned short f2h_(float a){
  _Float16 hv = (_Float16)a; return __builtin_bit_cast(unsigned short, hv);
}

#define Q4(acc, Wv, Uv) { acc=dot2u_((Uv).x,(Wv).x,acc); acc=dot2u_((Uv).y,(Wv).y,acc); \
                          acc=dot2u_((Uv).z,(Wv).z,acc); acc=dot2u_((Uv).w,(Wv).w,acc); }

// ---------------- stats + x_comp ----------------
__global__ __launch_bounds__(256) void k_stats(
    const float* __restrict__ values, const float* __restrict__ masks,
    const int* __restrict__ lengths,
    float* __restrict__ x_comp, float* __restrict__ stats)
{
  const int b = blockIdx.x;
  const int v = threadIdx.x & 31;
  const int g = threadIdx.x >> 5;
  const int len = lengths[b];
  const float* vb = values + (size_t)b*NT*NV;
  const float* mb = masks  + (size_t)b*NT*NV;
  float* xb = x_comp + (size_t)b*NT*NV;
  float s_m=0.f, s_mv=0.f, s_v=0.f, s_v2=0.f;
  for (int t=g; t<NT; t+=8){
    float val = vb[t*NV+v];
    float m   = mb[t*NV+v];
    float xp  = (t==0) ? vb[v] : vb[(t-1)*NV+v];
    float pm  = (t<len) ? 1.0f : 0.0f;
    xb[t*NV+v] = (m*val + (1.0f-m)*xp)*pm;
    s_m += m; s_mv += m*val; s_v += val; s_v2 += val*val;
  }
  __shared__ float red[4][8][32];
  red[0][g][v]=s_m; red[1][g][v]=s_mv; red[2][g][v]=s_v; red[3][g][v]=s_v2;
  __syncthreads();
  if (g==0){
    float a0=0,a1=0,a2=0,a3=0;
    #pragma unroll
    for(int i=0;i<8;i++){ a0+=red[0][i][v]; a1+=red[1][i][v]; a2+=red[2][i][v]; a3+=red[3][i][v]; }
    float msum = fmaxf(a0, 1.0f);
    float mean = a1/msum;
    float dss  = a3 - 2.0f*mean*a2 + (float)NT*mean*mean;
    float var  = (msum > 1.0f) ? dss/(msum-1.0f) : 0.0f;
    float sd   = sqrtf(fmaxf(var, 0.0f));
    float miss = 1.0f - a0 / fmaxf((float)len, 1.0f);
    float* st = stats + b*97;
    if (v==0) st[0] = (float)len;
    st[1+v]=mean; st[33+v]=sd; st[65+v]=miss;
  }
}

// ---------------- context MLP ----------------
__global__ __launch_bounds__(64) void k_cmlp(
    const float* __restrict__ stats,
    const float* __restrict__ W1, const float* __restrict__ b1,
    const float* __restrict__ W2, const float* __restrict__ b2,
    float* __restrict__ ctx)
{
  const int b = blockIdx.x;
  const int j = threadIdx.x;
  __shared__ float st[97];
  __shared__ float hm[64];
  for (int k=j; k<97; k+=64) st[k] = stats[b*97+k];
  __syncthreads();
  float a0=b1[j], a1=0.f, a2=0.f, a3=0.f;
  #pragma unroll
  for (int k=0; k<96; k+=4){
    a0 += st[k]*W1[j*97+k];     a1 += st[k+1]*W1[j*97+k+1];
    a2 += st[k+2]*W1[j*97+k+2]; a3 += st[k+3]*W1[j*97+k+3];
  }
  a0 += st[96]*W1[j*97+96];
  hm[j] = fmaxf((a0+a1)+(a2+a3), 0.0f);
  __syncthreads();
  if (j < 32){
    float c0_=b2[j], c1=0.f, c2=0.f, c3=0.f;
    #pragma unroll
    for (int k=0;k<64;k+=4){
      c0_ += hm[k]*W2[j*64+k];    c1 += hm[k+1]*W2[j*64+k+1];
      c2 += hm[k+2]*W2[j*64+k+2]; c3 += hm[k+3]*W2[j*64+k+3];
    }
    ctx[b*64+j] = (c0_+c1)+(c2+c3);
  }
}

// ---------------- GRU x-part GEMM: gig[b*T][96] f16 ----------------
__global__ __launch_bounds__(128) void k_gigru(
    const float* __restrict__ x_comp, const float* __restrict__ rain_f,
    const float* __restrict__ rain_b,
    const float* __restrict__ Wih, const float* __restrict__ bih,
    unsigned short* __restrict__ gig)
{
  __shared__ uint32_t WT[48][98];
  __shared__ __align__(16) uint32_t us[8][48];
  const int tid = threadIdx.x;
  for (int idx = tid; idx < 48*96; idx += 128){
    const int k = idx / 96, col = idx - k*96;
    WT[k][col] = pack2u_(Wih[(size_t)col*96 + 2*k], Wih[(size_t)col*96 + 2*k + 1]);
  }
  const float bias = (tid < 96) ? bih[tid] : 0.f;
  __syncthreads();
  const int NR = NB*NT;
  for (int r0 = blockIdx.x*8; r0 < NR; r0 += gridDim.x*8){
    __syncthreads();
    for (int idx = tid; idx < 8*48; idx += 128){
      const int r = idx / 48, w = idx - r*48;
      const size_t row = (size_t)r0 + r;
      const int i0 = 2*w, i1 = 2*w+1;
      const float a = (i0<32)? x_comp[row*32+i0] : (i0<64 ? rain_f[row*32+i0-32] : rain_b[row*32+i0-64]);
      const float c = (i1<32)? x_comp[row*32+i1] : (i1<64 ? rain_f[row*32+i1-32] : rain_b[row*32+i1-64]);
      us[r][w] = pack2u_(a, c);
    }
    __syncthreads();
    if (tid < 96){
      #pragma unroll
      for (int r=0;r<8;r++){
        const uint4* U = (const uint4*)us[r];
        float acc = bias;
        #pragma unroll
        for (int k4=0;k4<12;k4++){
          const uint4 u4 = U[k4];
          acc = dot2u_(u4.x, WT[4*k4][tid],   acc);
          acc = dot2u_(u4.y, WT[4*k4+1][tid], acc);
          acc = dot2u_(u4.z, WT[4*k4+2][tid], acc);
          acc = dot2u_(u4.w, WT[4*k4+3][tid], acc);
        }
        gig[((size_t)r0+r)*96 + tid] = f2h_(acc);
      }
    }
  }
}

// ---------------- GRU scan: single wave per batch, MFMA A-frags resident,
// in-register gate combine (r17 trick): lane l picks j4=l&3 and owns elements
// e0=(l>>4)*4+j4 (tiles 0/2/4 = r/z/n lo) and e1=e0+16 (tiles 1/3/5).
// No gbuf, ONE sync per step, hbuf double-buffered. ----------------
__global__ __launch_bounds__(64,4) void k_gru(
    const unsigned short* __restrict__ gig, const int* __restrict__ lengths,
    const float* __restrict__ Whh, const float* __restrict__ bhh,
    float* __restrict__ ctx)
{
  __shared__ __align__(16) _Float16 hbuf[2][32];
  const int b = blockIdx.x;
  const int l = threadIdx.x;
  const int arow = l & 15, ak = (l >> 4) * 8;
  const int rg = l >> 4, j4 = l & 3;
  const int crow = rg * 4;
  const int e0 = crow + j4, e1 = 16 + e0;
  const bool writer = ((l & 15) >> 2) == 0;
  f16x8 A0, A1, A2, A3, A4, A5;
  #define LDA(dst, mt) { const float* p_ = Whh + (size_t)((mt)*16 + arow)*32 + ak; \
    f16x8 t_; _Pragma("unroll") for (int e_=0;e_<8;++e_) t_[e_] = (_Float16)p_[e_]; dst = t_; }
  LDA(A0,0) LDA(A1,1) LDA(A2,2) LDA(A3,3) LDA(A4,4) LDA(A5,5)
  #undef LDA
  f32x4 bb0, bb1, bb2, bb3, bb4, bb5;
  #pragma unroll
  for (int j=0;j<4;j++){
    bb0[j] = bhh[0*16 + crow + j]; bb1[j] = bhh[1*16 + crow + j];
    bb2[j] = bhh[2*16 + crow + j]; bb3[j] = bhh[3*16 + crow + j];
    bb4[j] = bhh[4*16 + crow + j]; bb5[j] = bhh[5*16 + crow + j];
  }
  asm volatile("" ::: "memory");
  int len = lengths[b]; if (len > NT) len = NT;
  float h0v = 0.f, h1v = 0.f;
  if (l < 32) hbuf[0][l] = (_Float16)0.f;
  const unsigned short* gp = gig + (size_t)b*NT*96;
  float gir0=0.f, giz0=0.f, gin0=0.f, gir1=0.f, giz1=0.f, gin1=0.f;
  if (len > 0){
    gir0 = h2f_(gp[e0]); giz0 = h2f_(gp[32+e0]); gin0 = h2f_(gp[64+e0]);
    gir1 = h2f_(gp[e1]); giz1 = h2f_(gp[32+e1]); gin1 = h2f_(gp[64+e1]);
  }
  __syncthreads();
  for (int t=0; t<len; ++t){
    const int cur = t & 1;
    float nr0=0.f,nz0=0.f,nn0=0.f, nr1=0.f,nz1=0.f,nn1=0.f;
    if (t+1 < len){
      const unsigned short* gn = gp + (size_t)(t+1)*96;
      nr0 = h2f_(gn[e0]); nz0 = h2f_(gn[32+e0]); nn0 = h2f_(gn[64+e0]);
      nr1 = h2f_(gn[e1]); nz1 = h2f_(gn[32+e1]); nn1 = h2f_(gn[64+e1]);
    }
    const f16x8 bh = *(const f16x8*)&hbuf[cur][ak];
    f32x4 a0 = bb0, a1 = bb1, a2 = bb2, a3 = bb3, a4 = bb4, a5 = bb5;
    a0 = __builtin_amdgcn_mfma_f32_16x16x32_f16(A0, bh, a0, 0, 0, 0);
    a1 = __builtin_amdgcn_mfma_f32_16x16x32_f16(A1, bh, a1, 0, 0, 0);
    a2 = __builtin_amdgcn_mfma_f32_16x16x32_f16(A2, bh, a2, 0, 0, 0);
    a3 = __builtin_amdgcn_mfma_f32_16x16x32_f16(A3, bh, a3, 0, 0, 0);
    a4 = __builtin_amdgcn_mfma_f32_16x16x32_f16(A4, bh, a4, 0, 0, 0);
    a5 = __builtin_amdgcn_mfma_f32_16x16x32_f16(A5, bh, a5, 0, 0, 0);
    // in-register gates (values identical across the 16 broadcast columns)
    const float r0 = sigmoidf_(gir0 + a0[j4]);
    const float z0 = sigmoidf_(giz0 + a2[j4]);
    const float n0 = tanhf_(gin0 + r0*a4[j4]);
    h0v = (1.0f - z0)*n0 + z0*h0v;
    const float r1 = sigmoidf_(gir1 + a1[j4]);
    const float z1 = sigmoidf_(giz1 + a3[j4]);
    const float n1 = tanhf_(gin1 + r1*a5[j4]);
    h1v = (1.0f - z1)*n1 + z1*h1v;
    if (writer){
      hbuf[cur^1][e0] = (_Float16)h0v;
      hbuf[cur^1][e1] = (_Float16)h1v;
    }
    gir0=nr0; giz0=nz0; gin0=nn0;
    gir1=nr1; giz1=nz1; gin1=nn1;
    __syncthreads();
  }
  if (writer){
    ctx[b*64 + 32 + e0] = h0v;
    ctx[b*64 + 32 + e1] = h1v;
  }
}

// ---------------- init: h0/c0, ctx-part of LSTM gates, hidden seeds ----------------
__global__ __launch_bounds__(256) void k_init(
    const float* __restrict__ ctx,
    const float* __restrict__ initW, const float* __restrict__ initb,
    const float* __restrict__ WihF, const float* __restrict__ bihF, const float* __restrict__ bhhF,
    const float* __restrict__ WihB, const float* __restrict__ bihB, const float* __restrict__ bhhB,
    float* __restrict__ h0, float* __restrict__ c0,
    float* __restrict__ cgF, float* __restrict__ cgB,
    float* __restrict__ hidden)
{
  const int b = blockIdx.x;
  const int j = threadIdx.x;
  __shared__ __align__(16) float cv[64];
  if (j < 64) cv[j] = ctx[b*64+j];
  __syncthreads();
  {
    float4 f = {bihF[j]+bhhF[j], 0.f, 0.f, 0.f};
    float4 g = {bihB[j]+bhhB[j], 0.f, 0.f, 0.f};
    #pragma unroll
    for (int q=0;q<16;q++){
      const float4 cvv = *(const float4*)&cv[4*q];
      const float4 wf = *(const float4*)(WihF + (size_t)j*128 + 64 + 4*q);
      const float4 wb = *(const float4*)(WihB + (size_t)j*128 + 64 + 4*q);
      f.x += cvv.x*wf.x; f.y += cvv.y*wf.y; f.z += cvv.z*wf.z; f.w += cvv.w*wf.w;
      g.x += cvv.x*wb.x; g.y += cvv.y*wb.y; g.z += cvv.z*wb.z; g.w += cvv.w*wb.w;
    }
    cgF[b*256+j] = (f.x+f.y)+(f.z+f.w);
    cgB[b*256+j] = (g.x+g.y)+(g.z+g.w);
  }
  if (j < 128){
    float4 a = {initb[j], 0.f, 0.f, 0.f};
    #pragma unroll
    for (int q=0;q<16;q++){
      const float4 cvv = *(const float4*)&cv[4*q];
      const float4 w  = *(const float4*)(initW + (size_t)j*64 + 4*q);
      a.x += cvv.x*w.x; a.y += cvv.y*w.y; a.z += cvv.z*w.z; a.w += cvv.w*w.w;
    }
    float hv = (a.x+a.y)+(a.z+a.w);
    h0[b*128+j] = hv;
    c0[b*128+j] = tanhf_(hv);
    if (j < 64) hidden[(size_t)b*NT*128 + j] = hv;                                // fwd seed t=0
    else        hidden[(size_t)b*NT*128 + (size_t)(NT-1)*128 + 64 + (j-64)] = hv; // bwd seed t=T-1
  }
}

// ---------------- fused LSTM scan + feature-regression ----------------
// grid (256, 3), 256 thr, launch_bounds(256,2) [r18-proven]. hidb stride 40 f16 (r20-proven).
__global__ __launch_bounds__(256,2) void k_lstm_feat(
    const float* __restrict__ x_comp, const float* __restrict__ masks,
    const float* __restrict__ WihF, const float* __restrict__ WhhF,
    const float* __restrict__ WihB, const float* __restrict__ WhhB,
    const float* __restrict__ cgF, const float* __restrict__ cgB,
    const float* __restrict__ h0, const float* __restrict__ c0,
    const int* __restrict__ lengths,
    float* __restrict__ hidden,
    const float* __restrict__ feat_W, const float* __restrict__ feat_b,
    const float* __restrict__ nl1_W, const float* __restrict__ nl1_b,
    const float* __restrict__ nl2_W, const float* __restrict__ nl2_b,
    float* __restrict__ feat_imp)
{
  __shared__ __align__(16) _Float16 ubuf[2][64];
  __shared__ __align__(16) _Float16 hbuf[2][64];
  __shared__ __align__(16) _Float16 xbuf[16*32];
  __shared__ __align__(16) _Float16 hidb[32*16*40];     // stride 40 (padded)
  __shared__ __align__(16) float fbl[1024];
  __shared__ float fout[16*33];
  const int tid = threadIdx.x;
  if (blockIdx.y < 2){
    // ================= LSTM path (r17, unchanged) =================
    const int b = blockIdx.x, dir = blockIdx.y;
    const int l = tid & 63, wv = tid >> 6;
    const int eg = wv * 16;
    const int arow = l & 15, ak = (l >> 4) * 8;
    const int rowg = l >> 4;
    const int j4 = l & 3;
    const int elem = eg + rowg*4 + j4;
    const bool writer = ((l & 15) >> 2) == 0;
    const float* Wih = dir ? WihB : WihF;
    const float* Whh = dir ? WhhB : WhhF;
    f16x8 X0a,X0b,X1a,X1b,X2a,X2b,X3a,X3b;
    f16x8 H0a,H0b,H1a,H1b,H2a,H2b,H3a,H3b;
    #define LDFRAG(dst, base, ld, row, kk) { \
      const float* p_ = (base) + (size_t)(row)*(ld) + (kk); \
      const float4 v0_ = *(const float4*)p_; const float4 v1_ = *(const float4*)(p_+4); \
      f16x8 t_; t_[0]=(_Float16)v0_.x; t_[1]=(_Float16)v0_.y; t_[2]=(_Float16)v0_.z; t_[3]=(_Float16)v0_.w; \
      t_[4]=(_Float16)v1_.x; t_[5]=(_Float16)v1_.y; t_[6]=(_Float16)v1_.z; t_[7]=(_Float16)v1_.w; dst = t_; }
    LDFRAG(X0a, Wih, 128, 0*64+eg+arow, ak)    LDFRAG(X0b, Wih, 128, 0*64+eg+arow, 32+ak)
    LDFRAG(X1a, Wih, 128, 1*64+eg+arow, ak)    LDFRAG(X1b, Wih, 128, 1*64+eg+arow, 32+ak)
    LDFRAG(X2a, Wih, 128, 2*64+eg+arow, ak)    LDFRAG(X2b, Wih, 128, 2*64+eg+arow, 32+ak)
    LDFRAG(X3a, Wih, 128, 3*64+eg+arow, ak)    LDFRAG(X3b, Wih, 128, 3*64+eg+arow, 32+ak)
    LDFRAG(H0a, Whh, 64,  0*64+eg+arow, ak)    LDFRAG(H0b, Whh, 64,  0*64+eg+arow, 32+ak)
    LDFRAG(H1a, Whh, 64,  1*64+eg+arow, ak)    LDFRAG(H1b, Whh, 64,  1*64+eg+arow, 32+ak)
    LDFRAG(H2a, Whh, 64,  2*64+eg+arow, ak)    LDFRAG(H2b, Whh, 64,  2*64+eg+arow, 32+ak)
    LDFRAG(H3a, Whh, 64,  3*64+eg+arow, ak)    LDFRAG(H3b, Whh, 64,  3*64+eg+arow, 32+ak)
    #undef LDFRAG
    const float* cgp = (dir ? cgB : cgF) + (size_t)b*256;
    const int crow = rowg * 4;
    const f32x4 cgi = *(const f32x4*)(cgp + 0*64 + eg + crow);
    const f32x4 cgf = *(const f32x4*)(cgp + 1*64 + eg + crow);
    const f32x4 cgg = *(const f32x4*)(cgp + 2*64 + eg + crow);
    const f32x4 cgo = *(const f32x4*)(cgp + 3*64 + eg + crow);
    asm volatile("" ::: "memory");
    const int len = lengths[b];
    int nsteps = NT-1;
    if (dir == 0){ int e = len-1; if (e<0) e=0; if (e<nsteps) nsteps = e; }
    const float* xc = x_comp + (size_t)b*NT*NV;
    const float* mk = masks  + (size_t)b*NT*NV;
    float* hout = hidden + (size_t)b*NT*128 + dir*64;
    float cst = c0[(size_t)b*128 + dir*64 + elem];
    if (tid < 64) hbuf[0][tid] = (_Float16)h0[(size_t)b*128 + dir*64 + tid];
    if (tid >= 64 && tid < 96 && nsteps > 0){
      const int u = tid - 64;
      const int t0 = dir ? NT-1 : 0;
      const float2 v = (u<16) ? *(const float2*)(xc + t0*NV + 2*u)
                              : *(const float2*)(mk + t0*NV + 2*(u-16));
      ubuf[0][2*u] = (_Float16)v.x; ubuf[0][2*u+1] = (_Float16)v.y;
    }
    __syncthreads();
    for (int s=0; s<nsteps; ++s){
      const int cur = s & 1;
      float2 pre = {0.f, 0.f};
      const bool dopf = (tid >= 64 && tid < 96 && s+1 < nsteps);
      if (dopf){
        const int u = tid - 64;
        const int tn = dir ? (NT-2-s) : (s+1);
        pre = (u<16) ? *(const float2*)(xc + tn*NV + 2*u)
                     : *(const float2*)(mk + tn*NV + 2*(u-16));
      }
      const f16x8 bu0 = *(const f16x8*)&ubuf[cur][ak];
      const f16x8 bu1 = *(const f16x8*)&ubuf[cur][32+ak];
      const f16x8 bh0 = *(const f16x8*)&hbuf[cur][ak];
      const f16x8 bh1 = *(const f16x8*)&hbuf[cur][32+ak];
      f32x4 ai = cgi, af = cgf, ag = cgg, ao = cgo;
      ai = __builtin_amdgcn_mfma_f32_16x16x32_f16(X0a, bu0, ai, 0, 0, 0);
      af = __builtin_amdgcn_mfma_f32_16x16x32_f16(X1a, bu0, af, 0, 0, 0);
      ag = __builtin_amdgcn_mfma_f32_16x16x32_f16(X2a, bu0, ag, 0, 0, 0);
      ao = __builtin_amdgcn_mfma_f32_16x16x32_f16(X3a, bu0, ao, 0, 0, 0);
      ai = __builtin_amdgcn_mfma_f32_16x16x32_f16(X0b, bu1, ai, 0, 0, 0);
      af = __builtin_amdgcn_mfma_f32_16x16x32_f16(X1b, bu1, af, 0, 0, 0);
      ag = __builtin_amdgcn_mfma_f32_16x16x32_f16(X2b, bu1, ag, 0, 0, 0);
      ao = __builtin_amdgcn_mfma_f32_16x16x32_f16(X3b, bu1, ao, 0, 0, 0);
      ai = __builtin_amdgcn_mfma_f32_16x16x32_f16(H0a, bh0, ai, 0, 0, 0);
      af = __builtin_amdgcn_mfma_f32_16x16x32_f16(H1a, bh0, af, 0, 0, 0);
      ag = __builtin_amdgcn_mfma_f32_16x16x32_f16(H2a, bh0, ag, 0, 0, 0);
      ao = __builtin_amdgcn_mfma_f32_16x16x32_f16(H3a, bh0, ao, 0, 0, 0);
      ai = __builtin_amdgcn_mfma_f32_16x16x32_f16(H0b, bh1, ai, 0, 0, 0);
      af = __builtin_amdgcn_mfma_f32_16x16x32_f16(H1b, bh1, af, 0, 0, 0);
      ag = __builtin_amdgcn_mfma_f32_16x16x32_f16(H2b, bh1, ag, 0, 0, 0);
      ao = __builtin_amdgcn_mfma_f32_16x16x32_f16(H3b, bh1, ao, 0, 0, 0);
      const float gi = ai[j4], gf = af[j4], gg = ag[j4], go = ao[j4];
      cst = sigmoidf_(gf)*cst + sigmoidf_(gi)*tanhf_(gg);
      const float hh = sigmoidf_(go)*tanhf_(cst);
      if (writer){
        hbuf[cur^1][elem] = (_Float16)hh;
        const int outt = dir ? (NT-2-s) : (s+1);
        hout[(size_t)outt*128 + elem] = hh;
      }
      if (dopf){
        const int u = tid - 64;
        ubuf[cur^1][2*u]   = (_Float16)pre.x;
        ubuf[cur^1][2*u+1] = (_Float16)pre.y;
      }
      __syncthreads();
    }
    return;
  }
  // ================= feat path (4 waves, padded hidb) =================
  {
    const int l = tid & 63, wv = tid >> 6;         // wv 0..3
    const int fr = l >> 4, fc = l & 15;
    const int ak = fr * 8;
    f16x8 WA[16];
    #pragma unroll
    for (int q=0;q<16;q++){
      const int m_ = (wv*16 + q)*16 + fc;
      const int i_ = m_ >> 5;
      const float* s_ = feat_W + (size_t)m_*32 + ak;
      f16x8 t_;
      #pragma unroll
      for (int e_=0; e_<8; ++e_){
        float w_ = s_[e_];
        if (ak + e_ == i_) w_ = 0.f;
        t_[e_] = (_Float16)w_;
      }
      WA[q] = t_;
    }
    f16x8 NA0, NA1;
    {
      f16x8 t0, t1;
      #pragma unroll
      for (int e=0;e<8;e++){
        t0[e] = (_Float16)nl1_W[(fc)*32 + ak + e];
        t1[e] = (_Float16)nl1_W[(16 + fc)*32 + ak + e];
      }
      NA0 = t0; NA1 = t1;
    }
    f32x4 n1b0, n1b1;
    float n2w0[4], n2w1[4];
    #pragma unroll
    for (int j=0;j<4;j++){
      n1b0[j] = nl1_b[fr*4+j];
      n1b1[j] = nl1_b[16 + fr*4+j];
      n2w0[j] = nl2_W[fr*4+j];
      n2w1[j] = nl2_W[16 + fr*4+j];
    }
    const float n2b = nl2_b[0];
    for (int idx = tid; idx < 1024; idx += 256) fbl[idx] = feat_b[idx];
    asm volatile("" ::: "memory");
    const int NG = (NB*NT)/16;
    for (int g = blockIdx.x; g < NG; g += 256){
      const size_t r0 = (size_t)g*16;
      __syncthreads();
      {
        const int n0 = tid >> 4, v2 = (tid & 15)*2;   // 2 elems/thread
        const float2 xv = *(const float2*)&x_comp[(r0+n0)*32 + v2];
        xbuf[n0*32+v2]   = (_Float16)xv.x;
        xbuf[n0*32+v2+1] = (_Float16)xv.y;
      }
      __syncthreads();
      const f16x8 xB = *(const f16x8*)&xbuf[fc*32 + ak];
      #pragma unroll
      for (int q=0;q<16;q++){
        const int mt = wv*16 + q;
        f32x4 acc = {0.f,0.f,0.f,0.f};
        acc = __builtin_amdgcn_mfma_f32_16x16x32_f16(WA[q], xB, acc, 0, 0, 0);
        const int mbase = mt*16 + fr*4;
        const f32x4 fb4 = *(const f32x4*)&fbl[mbase];
        #pragma unroll
        for (int jj=0;jj<4;jj+=2){
          const int m0_ = mbase + jj;
          const int i_ = m0_ >> 5, h_ = m0_ & 31;
          const float v0_ = fmaxf(acc[jj]   + fb4[jj],   0.f);
          const float v1_ = fmaxf(acc[jj+1] + fb4[jj+1], 0.f);
          h2_t p; p.x = (_Float16)v0_; p.y = (_Float16)v1_;
          *(h2_t*)&hidb[(i_*16+fc)*40 + h_] = p;
        }
      }
      __syncthreads();
      float outv[8];
      #pragma unroll
      for (int q=0;q<8;q++){
        const int nt = wv*8 + q;
        const f16x8 hB = *(const f16x8*)&hidb[(nt*16+fc)*40 + ak];
        f32x4 z0 = n1b0, z1 = n1b1;
        z0 = __builtin_amdgcn_mfma_f32_16x16x32_f16(NA0, hB, z0, 0, 0, 0);
        z1 = __builtin_amdgcn_mfma_f32_16x16x32_f16(NA1, hB, z1, 0, 0, 0);
        float s = 0.f;
        #pragma unroll
        for (int j=0;j<4;j++){
          s += fmaxf(z0[j], 0.f)*n2w0[j];
          s += fmaxf(z1[j], 0.f)*n2w1[j];
        }
        s += __shfl_xor(s, 16);
        s += __shfl_xor(s, 32);
        outv[q] = s;
      }
      if (fr == 0){
        #pragma unroll
        for (int q=0;q<8;q++) fout[fc*33 + wv*8 + q] = outv[q] + n2b;
      }
      __syncthreads();
      feat_imp[r0*32 + tid]       = fout[(tid>>5)*33 + (tid&31)];
      feat_imp[r0*32 + 256 + tid] = fout[((tid+256)>>5)*33 + (tid&31)];
    }
  }
}

// ---------------- rnn_imp GEMM + fuse + final: LDS f16 rimp ----------------
__global__ __launch_bounds__(512) void k_final(
    const float* __restrict__ values, const float* __restrict__ masks,
    const float* __restrict__ feat_imp, const float* __restrict__ hidden,
    const float* __restrict__ rimp_W, const float* __restrict__ rimp_b,
    const float* __restrict__ fuse_W, const float* __restrict__ fuse_b,
    const int* __restrict__ lengths, float* __restrict__ out)
{
  const int tid = threadIdx.x;
  const int v = tid & 31;
  const int grp = (tid >> 5) & 7;
  const int half = tid >> 8;
  __shared__ uint32_t rpT[64][32];
  __shared__ __align__(16) uint32_t hrowp[8][64];
  __shared__ float rpart[8][32];
  __shared__ float bpart[8][32];
  for (int idx = tid; idx < 64*32; idx += 512){
    const int k = idx >> 5, vv = idx & 31;
    rpT[k][vv] = pack2u_(rimp_W[(size_t)vv*128 + 2*k], rimp_W[(size_t)vv*128 + 2*k+1]);
  }
  const float4* F4 = (const float4*)(fuse_W + (size_t)v*64 + 32);
  float fconst = 0.f;
  if (!half){
    fconst = fuse_b[v];
    #pragma unroll
    for (int q=0;q<8;q++){
      const float4 fw = *(const float4*)(fuse_W + (size_t)v*64 + 4*q);
      fconst += (fw.x+fw.y)+(fw.z+fw.w);
    }
  }
  const float rbias = rimp_b[v];
  __syncthreads();
  const int NOCT = (NB*NT)/8;
  for (int oc = blockIdx.x; oc < NOCT; oc += gridDim.x){
    const size_t base = (size_t)oc*8;
    __syncthreads();
    if (tid < 256){
      const float4 hv = ((const float4*)(hidden + base*128))[tid];
      const int row = tid >> 5;
      const int w0 = (tid & 31) << 1;
      hrowp[row][w0]   = pack2u_(hv.x, hv.y);
      hrowp[row][w0+1] = pack2u_(hv.z, hv.w);
    }
    __syncthreads();
    const size_t r = base + grp;
    float a = half ? 0.f : rbias;
    {
      const uint4* hp4 = (const uint4*)&hrowp[grp][half*32];
      #pragma unroll
      for (int c4=0;c4<8;c4++){
        const uint4 H = hp4[c4];
        a = dot2u_(H.x, rpT[half*32 + 4*c4][v],     a);
        a = dot2u_(H.y, rpT[half*32 + 4*c4 + 1][v], a);
        a = dot2u_(H.z, rpT[half*32 + 4*c4 + 2][v], a);
        a = dot2u_(H.w, rpT[half*32 + 4*c4 + 3][v], a);
      }
    }
    if (half){
      rpart[grp][v] = a;
      const float* mrow = masks + r*32;
      float m0=0,m1=0,m2=0,m3=0;
      #pragma unroll
      for (int q=0;q<8;q++){
        const float4 mv = *(const float4*)(mrow + 4*q);
        const float4 fv = F4[q];
        m0 = fmaf(mv.x, fv.x, m0); m1 = fmaf(mv.y, fv.y, m1);
        m2 = fmaf(mv.z, fv.z, m2); m3 = fmaf(mv.w, fv.w, m3);
      }
      bpart[grp][v] = (m0+m1)+(m2+m3);
    }
    __syncthreads();
    if (!half){
      const int bb = (int)(r >> 9);
      const int t  = (int)(r & 511);
      const int len = lengths[bb];
      const float rimp = a + rpart[grp][v];
      const float beta = sigmoidf_(fconst + bpart[grp][v]);
      const float fi = feat_imp[r*32+v];
      const float m  = masks[r*32+v];
      const float val= values[r*32+v];
      const float fz = beta*fi + (1.0f-beta)*rimp;
      const float o = m*val + (1.0f-m)*fz;
      out[r*32+v] = (t < len) ? o : 0.0f;
    }
  }
}

extern "C" void kernel_launch(void* const* d_in, const int* in_sizes, int n_in,
                              void* d_out, int out_size, void* d_ws, size_t ws_size,
                              hipStream_t stream) {
  const float* values   = (const float*)d_in[0];
  const float* masks    = (const float*)d_in[1];
  const float* rain_f   = (const float*)d_in[2];
  const float* rain_b   = (const float*)d_in[3];
  const float* cmlp_W1  = (const float*)d_in[4];
  const float* cmlp_b1  = (const float*)d_in[5];
  const float* cmlp_W2  = (const float*)d_in[6];
  const float* cmlp_b2  = (const float*)d_in[7];
  const float* gru_Wih  = (const float*)d_in[8];
  const float* gru_Whh  = (const float*)d_in[9];
  const float* gru_bih  = (const float*)d_in[10];
  const float* gru_bhh  = (const float*)d_in[11];
  const float* init_W   = (const float*)d_in[12];
  const float* init_b   = (const float*)d_in[13];
  const float* lstmf_Wih= (const float*)d_in[14];
  const float* lstmf_Whh= (const float*)d_in[15];
  const float* lstmf_bih= (const float*)d_in[16];
  const float* lstmf_bhh= (const float*)d_in[17];
  const float* lstmb_Wih= (const float*)d_in[18];
  const float* lstmb_Whh= (const float*)d_in[19];
  const float* lstmb_bih= (const float*)d_in[20];
  const float* lstmb_bhh= (const float*)d_in[21];
  const float* rimp_W   = (const float*)d_in[22];
  const float* rimp_b   = (const float*)d_in[23];
  const float* feat_W   = (const float*)d_in[24];
  const float* feat_b   = (const float*)d_in[25];
  const float* nl1_W    = (const float*)d_in[26];
  const float* nl1_b    = (const float*)d_in[27];
  const float* nl2_W    = (const float*)d_in[28];
  const float* nl2_b    = (const float*)d_in[29];
  const float* fuse_W   = (const float*)d_in[30];
  const float* fuse_b   = (const float*)d_in[31];
  const int*   lengths  = (const int*)d_in[32];
  float* out = (float*)d_out;

  float* ws       = (float*)d_ws;
  float* x_comp   = ws;                                   // B*T*V
  float* stats    = x_comp + (size_t)NB*NT*NV;            // B*97
  float* ctx      = stats + NB*97;                        // B*64
  float* h0       = ctx + NB*64;                          // B*128
  float* c0      = h0 + NB*128;                           // B*128
  float* cgF      = c0 + NB*128;                          // B*256
  float* cgB      = cgF + NB*256;                         // B*256
  float* hidden   = cgB + NB*256;                         // B*T*128
  float* feat_imp = hidden + (size_t)NB*NT*128;           // B*T*V
  unsigned short* gig = (unsigned short*)(feat_imp + (size_t)NB*NT*NV); // B*T*96 f16
  // total ~127 MB

  k_stats<<<NB, 256, 0, stream>>>(values, masks, lengths, x_comp, stats);
  k_gigru<<<2048, 128, 0, stream>>>(x_comp, rain_f, rain_b, gru_Wih, gru_bih, gig);
  k_cmlp<<<NB, 64, 0, stream>>>(stats, cmlp_W1, cmlp_b1, cmlp_W2, cmlp_b2, ctx);
  k_gru<<<NB, 64, 0, stream>>>(gig, lengths, gru_Whh, gru_bhh, ctx);
  k_init<<<NB, 256, 0, stream>>>(ctx, init_W, init_b,
                                 lstmf_Wih, lstmf_bih, lstmf_bhh,
                                 lstmb_Wih, lstmb_bih, lstmb_bhh,
                                 h0, c0, cgF, cgB, hidden);
  dim3 lgrid(NB, 3);
  k_lstm_feat<<<lgrid, 256, 0, stream>>>(x_comp, masks,
                                         lstmf_Wih, lstmf_Whh, lstmb_Wih, lstmb_Whh,
                                         cgF, cgB, h0, c0, lengths, hidden,
                                         feat_W, feat_b, nl1_W, nl1_b, nl2_W, nl2_b, feat_imp);
  k_final<<<2048, 512, 0, stream>>>(values, masks, feat_imp, hidden,
                                    rimp_W, rimp_b, fuse_W, fuse_b, lengths, out);
}

// Round 22
// 968.428 us; speedup vs baseline: 1.1240x; 1.1240x over previous
//
#include <hip/hip_runtime.h>
#include <cstddef>
#include <cstdint>

constexpr int NB = 256;
constexpr int NT = 512;
constexpr int NV = 32;

typedef _Float16 h2_t __attribute__((ext_vector_type(2)));
typedef _Float16 f16x8 __attribute__((ext_vector_type(8)));
typedef float f32x4 __attribute__((ext_vector_type(4)));

__device__ __forceinline__ float sigmoidf_(float x){ return 1.0f/(1.0f+__expf(-x)); }
__device__ __forceinline__ float tanhf_(float x){ return 1.0f - 2.0f/(__expf(2.0f*x)+1.0f); }

__device__ __forceinline__ uint32_t pack2u_(float a, float b){
  h2_t r; r.x=(_Float16)a; r.y=(_Float16)b; return __builtin_bit_cast(uint32_t, r);
}
__device__ __forceinline__ float dot2u_(uint32_t u, uint32_t w, float c){
#if __has_builtin(__builtin_amdgcn_fdot2)
  return __builtin_amdgcn_fdot2(__builtin_bit_cast(h2_t,u), __builtin_bit_cast(h2_t,w), c, false);
#else
  h2_t a=__builtin_bit_cast(h2_t,u), b=__builtin_bit_cast(h2_t,b);
  return c + (float)a.x*(float)b.x + (float)a.y*(float)b.y;
#endif
}
__device__ __forceinline__ float h2f_(unsigned short u){
  _Float16 hv = __builtin_bit_cast(_Float16, u); return (float)hv;
}
__device__ __forceinline__ unsigned short f2h_(float a){
  _Float16 hv = (_Float16)a; return __builtin_bit_cast(unsigned short, hv);
}

// ---------------- fused: stats+x_comp (blocks 0..255)  |  gigru w/ inline x (blocks 256..2303) ----------------
__global__ __launch_bounds__(256) void k_pre(
    const float* __restrict__ values, const float* __restrict__ masks,
    const float* __restrict__ rain_f, const float* __restrict__ rain_b,
    const int* __restrict__ lengths,
    const float* __restrict__ Wih, const float* __restrict__ bih,
    float* __restrict__ x_comp, float* __restrict__ stats,
    unsigned short* __restrict__ gig)
{
  __shared__ float red[4][8][32];
  __shared__ uint32_t WT[48][98];
  __shared__ __align__(16) uint32_t us[16][48];
  const int tid = threadIdx.x;
  if (blockIdx.x < NB){
    // ---------- stats role ----------
    const int b = blockIdx.x;
    const int v = tid & 31;
    const int g = tid >> 5;
    const int len = lengths[b];
    const float* vb = values + (size_t)b*NT*NV;
    const float* mb = masks  + (size_t)b*NT*NV;
    float* xb = x_comp + (size_t)b*NT*NV;
    float s_m=0.f, s_mv=0.f, s_v=0.f, s_v2=0.f;
    for (int t=g; t<NT; t+=8){
      float val = vb[t*NV+v];
      float m   = mb[t*NV+v];
      float xp  = (t==0) ? vb[v] : vb[(t-1)*NV+v];
      float pm  = (t<len) ? 1.0f : 0.0f;
      xb[t*NV+v] = (m*val + (1.0f-m)*xp)*pm;
      s_m += m; s_mv += m*val; s_v += val; s_v2 += val*val;
    }
    red[0][g][v]=s_m; red[1][g][v]=s_mv; red[2][g][v]=s_v; red[3][g][v]=s_v2;
    __syncthreads();
    if (g==0){
      float a0=0,a1=0,a2=0,a3=0;
      #pragma unroll
      for(int i=0;i<8;i++){ a0+=red[0][i][v]; a1+=red[1][i][v]; a2+=red[2][i][v]; a3+=red[3][i][v]; }
      float msum = fmaxf(a0, 1.0f);
      float mean = a1/msum;
      float dss  = a3 - 2.0f*mean*a2 + (float)NT*mean*mean;
      float var  = (msum > 1.0f) ? dss/(msum-1.0f) : 0.0f;
      float sd   = sqrtf(fmaxf(var, 0.0f));
      float miss = 1.0f - a0 / fmaxf((float)len, 1.0f);
      float* st = stats + b*97;
      if (v==0) st[0] = (float)len;
      st[1+v]=mean; st[33+v]=sd; st[65+v]=miss;
    }
    return;
  }
  // ---------- gigru role (x_comp recomputed inline; no dependency on stats role) ----------
  const int bid = blockIdx.x - NB;   // 0..2047
  for (int idx = tid; idx < 48*96; idx += 256){
    const int k = idx / 96, col = idx - k*96;
    WT[k][col] = pack2u_(Wih[(size_t)col*96 + 2*k], Wih[(size_t)col*96 + 2*k + 1]);
  }
  const bool act = (tid < 192);
  const int grp = (tid >= 96) ? 1 : 0;
  const int col = tid - grp*96;
  const float bias = act ? bih[col] : 0.f;
  __syncthreads();
  const int NR = NB*NT;
  for (int r0 = bid*16; r0 < NR; r0 += 2048*16){
    __syncthreads();
    for (int idx = tid; idx < 16*48; idx += 256){
      const int r = idx / 48, w = idx - r*48;
      const size_t row = (size_t)r0 + r;
      const int bb = (int)(row >> 9), t = (int)(row & 511);
      const int len = lengths[bb];
      const float pm = (t < len) ? 1.0f : 0.0f;
      float vz[2];
      #pragma unroll
      for (int z=0; z<2; z++){
        const int i = 2*w + z;
        float a;
        if (i < 32){
          const float val = values[row*32 + i];
          const float m   = masks[row*32 + i];
          const float xp  = (t==0) ? values[((size_t)bb*NT)*32 + i] : values[(row-1)*32 + i];
          a = (m*val + (1.0f-m)*xp)*pm;
        } else if (i < 64){
          a = rain_f[row*32 + i - 32];
        } else {
          a = rain_b[row*32 + i - 64];
        }
        vz[z] = a;
      }
      us[r][w] = pack2u_(vz[0], vz[1]);
    }
    __syncthreads();
    if (act){
      #pragma unroll
      for (int r=0;r<8;r++){
        const int rr = grp*8 + r;
        const uint4* U = (const uint4*)us[rr];
        float acc = bias;
        #pragma unroll
        for (int k4=0;k4<12;k4++){
          const uint4 u4 = U[k4];
          acc = dot2u_(u4.x, WT[4*k4][col],   acc);
          acc = dot2u_(u4.y, WT[4*k4+1][col], acc);
          acc = dot2u_(u4.z, WT[4*k4+2][col], acc);
          acc = dot2u_(u4.w, WT[4*k4+3][col], acc);
        }
        gig[((size_t)r0+rr)*96 + col] = f2h_(acc);
      }
    }
  }
}

// ---------------- fused: GRU scan (blocks 0..255) | context MLP (blocks 256..511), 64 thr ----------------
__global__ __launch_bounds__(64,4) void k_gru_cmlp(
    const unsigned short* __restrict__ gig, const int* __restrict__ lengths,
    const float* __restrict__ Whh, const float* __restrict__ bhh,
    const float* __restrict__ stats,
    const float* __restrict__ W1, const float* __restrict__ b1,
    const float* __restrict__ W2, const float* __restrict__ b2,
    float* __restrict__ ctx)
{
  __shared__ __align__(16) _Float16 hbuf[2][32];
  __shared__ float st[97];
  __shared__ float hm[64];
  const int l = threadIdx.x;
  if (blockIdx.x >= NB){
    // ---------- cmlp role ----------
    const int b = blockIdx.x - NB;
    const int j = l;
    for (int k=j; k<97; k+=64) st[k] = stats[b*97+k];
    __syncthreads();
    float a0=b1[j], a1=0.f, a2=0.f, a3=0.f;
    #pragma unroll
    for (int k=0; k<96; k+=4){
      a0 += st[k]*W1[j*97+k];     a1 += st[k+1]*W1[j*97+k+1];
      a2 += st[k+2]*W1[j*97+k+2]; a3 += st[k+3]*W1[j*97+k+3];
    }
    a0 += st[96]*W1[j*97+96];
    hm[j] = fmaxf((a0+a1)+(a2+a3), 0.0f);
    __syncthreads();
    if (j < 32){
      float c0_=b2[j], c1=0.f, c2=0.f, c3=0.f;
      #pragma unroll
      for (int k=0;k<64;k+=4){
        c0_ += hm[k]*W2[j*64+k];    c1 += hm[k+1]*W2[j*64+k+1];
        c2 += hm[k+2]*W2[j*64+k+2]; c3 += hm[k+3]*W2[j*64+k+3];
      }
      ctx[b*64+j] = (c0_+c1)+(c2+c3);
    }
    return;
  }
  // ---------- gru role (r21-proven body) ----------
  const int b = blockIdx.x;
  const int arow = l & 15, ak = (l >> 4) * 8;
  const int rg = l >> 4, j4 = l & 3;
  const int crow = rg * 4;
  const int e0 = crow + j4, e1 = 16 + e0;
  const bool writer = ((l & 15) >> 2) == 0;
  f16x8 A0, A1, A2, A3, A4, A5;
  #define LDA(dst, mt) { const float* p_ = Whh + (size_t)((mt)*16 + arow)*32 + ak; \
    f16x8 t_; _Pragma("unroll") for (int e_=0;e_<8;++e_) t_[e_] = (_Float16)p_[e_]; dst = t_; }
  LDA(A0,0) LDA(A1,1) LDA(A2,2) LDA(A3,3) LDA(A4,4) LDA(A5,5)
  #undef LDA
  f32x4 bb0, bb1, bb2, bb3, bb4, bb5;
  #pragma unroll
  for (int j=0;j<4;j++){
    bb0[j] = bhh[0*16 + crow + j]; bb1[j] = bhh[1*16 + crow + j];
    bb2[j] = bhh[2*16 + crow + j]; bb3[j] = bhh[3*16 + crow + j];
    bb4[j] = bhh[4*16 + crow + j]; bb5[j] = bhh[5*16 + crow + j];
  }
  asm volatile("" ::: "memory");
  int len = lengths[b]; if (len > NT) len = NT;
  float h0v = 0.f, h1v = 0.f;
  if (l < 32) hbuf[0][l] = (_Float16)0.f;
  const unsigned short* gp = gig + (size_t)b*NT*96;
  float gir0=0.f, giz0=0.f, gin0=0.f, gir1=0.f, giz1=0.f, gin1=0.f;
  if (len > 0){
    gir0 = h2f_(gp[e0]); giz0 = h2f_(gp[32+e0]); gin0 = h2f_(gp[64+e0]);
    gir1 = h2f_(gp[e1]); giz1 = h2f_(gp[32+e1]); gin1 = h2f_(gp[64+e1]);
  }
  __syncthreads();
  for (int t=0; t<len; ++t){
    const int cur = t & 1;
    float nr0=0.f,nz0=0.f,nn0=0.f, nr1=0.f,nz1=0.f,nn1=0.f;
    if (t+1 < len){
      const unsigned short* gn = gp + (size_t)(t+1)*96;
      nr0 = h2f_(gn[e0]); nz0 = h2f_(gn[32+e0]); nn0 = h2f_(gn[64+e0]);
      nr1 = h2f_(gn[e1]); nz1 = h2f_(gn[32+e1]); nn1 = h2f_(gn[64+e1]);
    }
    const f16x8 bh = *(const f16x8*)&hbuf[cur][ak];
    f32x4 a0 = bb0, a1 = bb1, a2 = bb2, a3 = bb3, a4 = bb4, a5 = bb5;
    a0 = __builtin_amdgcn_mfma_f32_16x16x32_f16(A0, bh, a0, 0, 0, 0);
    a1 = __builtin_amdgcn_mfma_f32_16x16x32_f16(A1, bh, a1, 0, 0, 0);
    a2 = __builtin_amdgcn_mfma_f32_16x16x32_f16(A2, bh, a2, 0, 0, 0);
    a3 = __builtin_amdgcn_mfma_f32_16x16x32_f16(A3, bh, a3, 0, 0, 0);
    a4 = __builtin_amdgcn_mfma_f32_16x16x32_f16(A4, bh, a4, 0, 0, 0);
    a5 = __builtin_amdgcn_mfma_f32_16x16x32_f16(A5, bh, a5, 0, 0, 0);
    const float r0 = sigmoidf_(gir0 + a0[j4]);
    const float z0 = sigmoidf_(giz0 + a2[j4]);
    const float n0 = tanhf_(gin0 + r0*a4[j4]);
    h0v = (1.0f - z0)*n0 + z0*h0v;
    const float r1 = sigmoidf_(gir1 + a1[j4]);
    const float z1 = sigmoidf_(giz1 + a3[j4]);
    const float n1 = tanhf_(gin1 + r1*a5[j4]);
    h1v = (1.0f - z1)*n1 + z1*h1v;
    if (writer){
      hbuf[cur^1][e0] = (_Float16)h0v;
      hbuf[cur^1][e1] = (_Float16)h1v;
    }
    gir0=nr0; giz0=nz0; gin0=nn0;
    gir1=nr1; giz1=nz1; gin1=nn1;
    __syncthreads();
  }
  if (writer){
    ctx[b*64 + 32 + e0] = h0v;
    ctx[b*64 + 32 + e1] = h1v;
  }
}

// ---------------- init: h0/c0, ctx-part of LSTM gates, hidden seeds ----------------
__global__ __launch_bounds__(256) void k_init(
    const float* __restrict__ ctx,
    const float* __restrict__ initW, const float* __restrict__ initb,
    const float* __restrict__ WihF, const float* __restrict__ bihF, const float* __restrict__ bhhF,
    const float* __restrict__ WihB, const float* __restrict__ bihB, const float* __restrict__ bhhB,
    float* __restrict__ h0, float* __restrict__ c0,
    float* __restrict__ cgF, float* __restrict__ cgB,
    float* __restrict__ hidden)
{
  const int b = blockIdx.x;
  const int j = threadIdx.x;
  __shared__ __align__(16) float cv[64];
  if (j < 64) cv[j] = ctx[b*64+j];
  __syncthreads();
  {
    float4 f = {bihF[j]+bhhF[j], 0.f, 0.f, 0.f};
    float4 g = {bihB[j]+bhhB[j], 0.f, 0.f, 0.f};
    #pragma unroll
    for (int q=0;q<16;q++){
      const float4 cvv = *(const float4*)&cv[4*q];
      const float4 wf = *(const float4*)(WihF + (size_t)j*128 + 64 + 4*q);
      const float4 wb = *(const float4*)(WihB + (size_t)j*128 + 64 + 4*q);
      f.x += cvv.x*wf.x; f.y += cvv.y*wf.y; f.z += cvv.z*wf.z; f.w += cvv.w*wf.w;
      g.x += cvv.x*wb.x; g.y += cvv.y*wb.y; g.z += cvv.z*wb.z; g.w += cvv.w*wb.w;
    }
    cgF[b*256+j] = (f.x+f.y)+(f.z+f.w);
    cgB[b*256+j] = (g.x+g.y)+(g.z+g.w);
  }
  if (j < 128){
    float4 a = {initb[j], 0.f, 0.f, 0.f};
    #pragma unroll
    for (int q=0;q<16;q++){
      const float4 cvv = *(const float4*)&cv[4*q];
      const float4 w  = *(const float4*)(initW + (size_t)j*64 + 4*q);
      a.x += cvv.x*w.x; a.y += cvv.y*w.y; a.z += cvv.z*w.z; a.w += cvv.w*w.w;
    }
    float hv = (a.x+a.y)+(a.z+a.w);
    h0[b*128+j] = hv;
    c0[b*128+j] = tanhf_(hv);
    if (j < 64) hidden[(size_t)b*NT*128 + j] = hv;                                // fwd seed t=0
    else        hidden[(size_t)b*NT*128 + (size_t)(NT-1)*128 + 64 + (j-64)] = hv; // bwd seed t=T-1
  }
}

// ---------------- fused LSTM scan + feature-regression (r20-proven) ----------------
__global__ __launch_bounds__(256,2) void k_lstm_feat(
    const float* __restrict__ x_comp, const float* __restrict__ masks,
    const float* __restrict__ WihF, const float* __restrict__ WhhF,
    const float* __restrict__ WihB, const float* __restrict__ WhhB,
    const float* __restrict__ cgF, const float* __restrict__ cgB,
    const float* __restrict__ h0, const float* __restrict__ c0,
    const int* __restrict__ lengths,
    float* __restrict__ hidden,
    const float* __restrict__ feat_W, const float* __restrict__ feat_b,
    const float* __restrict__ nl1_W, const float* __restrict__ nl1_b,
    const float* __restrict__ nl2_W, const float* __restrict__ nl2_b,
    float* __restrict__ feat_imp)
{
  __shared__ __align__(16) _Float16 ubuf[2][64];
  __shared__ __align__(16) _Float16 hbuf[2][64];
  __shared__ __align__(16) _Float16 xbuf[16*32];
  __shared__ __align__(16) _Float16 hidb[32*16*40];     // stride 40 (padded)
  __shared__ __align__(16) float fbl[1024];
  __shared__ float fout[16*33];
  const int tid = threadIdx.x;
  if (blockIdx.y < 2){
    const int b = blockIdx.x, dir = blockIdx.y;
    const int l = tid & 63, wv = tid >> 6;
    const int eg = wv * 16;
    const int arow = l & 15, ak = (l >> 4) * 8;
    const int rowg = l >> 4;
    const int j4 = l & 3;
    const int elem = eg + rowg*4 + j4;
    const bool writer = ((l & 15) >> 2) == 0;
    const float* Wih = dir ? WihB : WihF;
    const float* Whh = dir ? WhhB : WhhF;
    f16x8 X0a,X0b,X1a,X1b,X2a,X2b,X3a,X3b;
    f16x8 H0a,H0b,H1a,H1b,H2a,H2b,H3a,H3b;
    #define LDFRAG(dst, base, ld, row, kk) { \
      const float* p_ = (base) + (size_t)(row)*(ld) + (kk); \
      const float4 v0_ = *(const float4*)p_; const float4 v1_ = *(const float4*)(p_+4); \
      f16x8 t_; t_[0]=(_Float16)v0_.x; t_[1]=(_Float16)v0_.y; t_[2]=(_Float16)v0_.z; t_[3]=(_Float16)v0_.w; \
      t_[4]=(_Float16)v1_.x; t_[5]=(_Float16)v1_.y; t_[6]=(_Float16)v1_.z; t_[7]=(_Float16)v1_.w; dst = t_; }
    LDFRAG(X0a, Wih, 128, 0*64+eg+arow, ak)    LDFRAG(X0b, Wih, 128, 0*64+eg+arow, 32+ak)
    LDFRAG(X1a, Wih, 128, 1*64+eg+arow, ak)    LDFRAG(X1b, Wih, 128, 1*64+eg+arow, 32+ak)
    LDFRAG(X2a, Wih, 128, 2*64+eg+arow, ak)    LDFRAG(X2b, Wih, 128, 2*64+eg+arow, 32+ak)
    LDFRAG(X3a, Wih, 128, 3*64+eg+arow, ak)    LDFRAG(X3b, Wih, 128, 3*64+eg+arow, 32+ak)
    LDFRAG(H0a, Whh, 64,  0*64+eg+arow, ak)    LDFRAG(H0b, Whh, 64,  0*64+eg+arow, 32+ak)
    LDFRAG(H1a, Whh, 64,  1*64+eg+arow, ak)    LDFRAG(H1b, Whh, 64,  1*64+eg+arow, 32+ak)
    LDFRAG(H2a, Whh, 64,  2*64+eg+arow, ak)    LDFRAG(H2b, Whh, 64,  2*64+eg+arow, 32+ak)
    LDFRAG(H3a, Whh, 64,  3*64+eg+arow, ak)    LDFRAG(H3b, Whh, 64,  3*64+eg+arow, 32+ak)
    #undef LDFRAG
    const float* cgp = (dir ? cgB : cgF) + (size_t)b*256;
    const int crow = rowg * 4;
    const f32x4 cgi = *(const f32x4*)(cgp + 0*64 + eg + crow);
    const f32x4 cgf = *(const f32x4*)(cgp + 1*64 + eg + crow);
    const f32x4 cgg = *(const f32x4*)(cgp + 2*64 + eg + crow);
    const f32x4 cgo = *(const f32x4*)(cgp + 3*64 + eg + crow);
    asm volatile("" ::: "memory");
    const int len = lengths[b];
    int nsteps = NT-1;
    if (dir == 0){ int e = len-1; if (e<0) e=0; if (e<nsteps) nsteps = e; }
    const float* xc = x_comp + (size_t)b*NT*NV;
    const float* mk = masks  + (size_t)b*NT*NV;
    float* hout = hidden + (size_t)b*NT*128 + dir*64;
    float cst = c0[(size_t)b*128 + dir*64 + elem];
    if (tid < 64) hbuf[0][tid] = (_Float16)h0[(size_t)b*128 + dir*64 + tid];
    if (tid >= 64 && tid < 96 && nsteps > 0){
      const int u = tid - 64;
      const int t0 = dir ? NT-1 : 0;
      const float2 v = (u<16) ? *(const float2*)(xc + t0*NV + 2*u)
                              : *(const float2*)(mk + t0*NV + 2*(u-16));
      ubuf[0][2*u] = (_Float16)v.x; ubuf[0][2*u+1] = (_Float16)v.y;
    }
    __syncthreads();
    for (int s=0; s<nsteps; ++s){
      const int cur = s & 1;
      float2 pre = {0.f, 0.f};
      const bool dopf = (tid >= 64 && tid < 96 && s+1 < nsteps);
      if (dopf){
        const int u = tid - 64;
        const int tn = dir ? (NT-2-s) : (s+1);
        pre = (u<16) ? *(const float2*)(xc + tn*NV + 2*u)
                     : *(const float2*)(mk + tn*NV + 2*(u-16));
      }
      const f16x8 bu0 = *(const f16x8*)&ubuf[cur][ak];
      const f16x8 bu1 = *(const f16x8*)&ubuf[cur][32+ak];
      const f16x8 bh0 = *(const f16x8*)&hbuf[cur][ak];
      const f16x8 bh1 = *(const f16x8*)&hbuf[cur][32+ak];
      f32x4 ai = cgi, af = cgf, ag = cgg, ao = cgo;
      ai = __builtin_amdgcn_mfma_f32_16x16x32_f16(X0a, bu0, ai, 0, 0, 0);
      af = __builtin_amdgcn_mfma_f32_16x16x32_f16(X1a, bu0, af, 0, 0, 0);
      ag = __builtin_amdgcn_mfma_f32_16x16x32_f16(X2a, bu0, ag, 0, 0, 0);
      ao = __builtin_amdgcn_mfma_f32_16x16x32_f16(X3a, bu0, ao, 0, 0, 0);
      ai = __builtin_amdgcn_mfma_f32_16x16x32_f16(X0b, bu1, ai, 0, 0, 0);
      af = __builtin_amdgcn_mfma_f32_16x16x32_f16(X1b, bu1, af, 0, 0, 0);
      ag = __builtin_amdgcn_mfma_f32_16x16x32_f16(X2b, bu1, ag, 0, 0, 0);
      ao = __builtin_amdgcn_mfma_f32_16x16x32_f16(X3b, bu1, ao, 0, 0, 0);
      ai = __builtin_amdgcn_mfma_f32_16x16x32_f16(H0a, bh0, ai, 0, 0, 0);
      af = __builtin_amdgcn_mfma_f32_16x16x32_f16(H1a, bh0, af, 0, 0, 0);
      ag = __builtin_amdgcn_mfma_f32_16x16x32_f16(H2a, bh0, ag, 0, 0, 0);
      ao = __builtin_amdgcn_mfma_f32_16x16x32_f16(H3a, bh0, ao, 0, 0, 0);
      ai = __builtin_amdgcn_mfma_f32_16x16x32_f16(H0b, bh1, ai, 0, 0, 0);
      af = __builtin_amdgcn_mfma_f32_16x16x32_f16(H1b, bh1, af, 0, 0, 0);
      ag = __builtin_amdgcn_mfma_f32_16x16x32_f16(H2b, bh1, ag, 0, 0, 0);
      ao = __builtin_amdgcn_mfma_f32_16x16x32_f16(H3b, bh1, ao, 0, 0, 0);
      const float gi = ai[j4], gf = af[j4], gg = ag[j4], go = ao[j4];
      cst = sigmoidf_(gf)*cst + sigmoidf_(gi)*tanhf_(gg);
      const float hh = sigmoidf_(go)*tanhf_(cst);
      if (writer){
        hbuf[cur^1][elem] = (_Float16)hh;
        const int outt = dir ? (NT-2-s) : (s+1);
        hout[(size_t)outt*128 + elem] = hh;
      }
      if (dopf){
        const int u = tid - 64;
        ubuf[cur^1][2*u]   = (_Float16)pre.x;
        ubuf[cur^1][2*u+1] = (_Float16)pre.y;
      }
      __syncthreads();
    }
    return;
  }
  // ================= feat path (4 waves, padded hidb) =================
  {
    const int l = tid & 63, wv = tid >> 6;         // wv 0..3
    const int fr = l >> 4, fc = l & 15;
    const int ak = fr * 8;
    f16x8 WA[16];
    #pragma unroll
    for (int q=0;q<16;q++){
      const int m_ = (wv*16 + q)*16 + fc;
      const int i_ = m_ >> 5;
      const float* s_ = feat_W + (size_t)m_*32 + ak;
      f16x8 t_;
      #pragma unroll
      for (int e_=0; e_<8; ++e_){
        float w_ = s_[e_];
        if (ak + e_ == i_) w_ = 0.f;
        t_[e_] = (_Float16)w_;
      }
      WA[q] = t_;
    }
    f16x8 NA0, NA1;
    {
      f16x8 t0, t1;
      #pragma unroll
      for (int e=0;e<8;e++){
        t0[e] = (_Float16)nl1_W[(fc)*32 + ak + e];
        t1[e] = (_Float16)nl1_W[(16 + fc)*32 + ak + e];
      }
      NA0 = t0; NA1 = t1;
    }
    f32x4 n1b0, n1b1;
    float n2w0[4], n2w1[4];
    #pragma unroll
    for (int j=0;j<4;j++){
      n1b0[j] = nl1_b[fr*4+j];
      n1b1[j] = nl1_b[16 + fr*4+j];
      n2w0[j] = nl2_W[fr*4+j];
      n2w1[j] = nl2_W[16 + fr*4+j];
    }
    const float n2b = nl2_b[0];
    for (int idx = tid; idx < 1024; idx += 256) fbl[idx] = feat_b[idx];
    asm volatile("" ::: "memory");
    const int NG = (NB*NT)/16;
    for (int g = blockIdx.x; g < NG; g += 256){
      const size_t r0 = (size_t)g*16;
      __syncthreads();
      {
        const int n0 = tid >> 4, v2 = (tid & 15)*2;   // 2 elems/thread
        const float2 xv = *(const float2*)&x_comp[(r0+n0)*32 + v2];
        xbuf[n0*32+v2]   = (_Float16)xv.x;
        xbuf[n0*32+v2+1] = (_Float16)xv.y;
      }
      __syncthreads();
      const f16x8 xB = *(const f16x8*)&xbuf[fc*32 + ak];
      #pragma unroll
      for (int q=0;q<16;q++){
        const int mt = wv*16 + q;
        f32x4 acc = {0.f,0.f,0.f,0.f};
        acc = __builtin_amdgcn_mfma_f32_16x16x32_f16(WA[q], xB, acc, 0, 0, 0);
        const int mbase = mt*16 + fr*4;
        const f32x4 fb4 = *(const f32x4*)&fbl[mbase];
        #pragma unroll
        for (int jj=0;jj<4;jj+=2){
          const int m0_ = mbase + jj;
          const int i_ = m0_ >> 5, h_ = m0_ & 31;
          const float v0_ = fmaxf(acc[jj]   + fb4[jj],   0.f);
          const float v1_ = fmaxf(acc[jj+1] + fb4[jj+1], 0.f);
          h2_t p; p.x = (_Float16)v0_; p.y = (_Float16)v1_;
          *(h2_t*)&hidb[(i_*16+fc)*40 + h_] = p;
        }
      }
      __syncthreads();
      float outv[8];
      #pragma unroll
      for (int q=0;q<8;q++){
        const int nt = wv*8 + q;
        const f16x8 hB = *(const f16x8*)&hidb[(nt*16+fc)*40 + ak];
        f32x4 z0 = n1b0, z1 = n1b1;
        z0 = __builtin_amdgcn_mfma_f32_16x16x32_f16(NA0, hB, z0, 0, 0, 0);
        z1 = __builtin_amdgcn_mfma_f32_16x16x32_f16(NA1, hB, z1, 0, 0, 0);
        float s = 0.f;
        #pragma unroll
        for (int j=0;j<4;j++){
          s += fmaxf(z0[j], 0.f)*n2w0[j];
          s += fmaxf(z1[j], 0.f)*n2w1[j];
        }
        s += __shfl_xor(s, 16);
        s += __shfl_xor(s, 32);
        outv[q] = s;
      }
      if (fr == 0){
        #pragma unroll
        for (int q=0;q<8;q++) fout[fc*33 + wv*8 + q] = outv[q] + n2b;
      }
      __syncthreads();
      feat_imp[r0*32 + tid]       = fout[(tid>>5)*33 + (tid&31)];
      feat_imp[r0*32 + 256 + tid] = fout[((tid+256)>>5)*33 + (tid&31)];
    }
  }
}

// ---------------- rnn_imp GEMM + fuse + final: LDS f16 rimp ----------------
__global__ __launch_bounds__(512) void k_final(
    const float* __restrict__ values, const float* __restrict__ masks,
    const float* __restrict__ feat_imp, const float* __restrict__ hidden,
    const float* __restrict__ rimp_W, const float* __restrict__ rimp_b,
    const float* __restrict__ fuse_W, const float* __restrict__ fuse_b,
    const int* __restrict__ lengths, float* __restrict__ out)
{
  const int tid = threadIdx.x;
  const int v = tid & 31;
  const int grp = (tid >> 5) & 7;
  const int half = tid >> 8;
  __shared__ uint32_t rpT[64][32];
  __shared__ __align__(16) uint32_t hrowp[8][64];
  __shared__ float rpart[8][32];
  __shared__ float bpart[8][32];
  for (int idx = tid; idx < 64*32; idx += 512){
    const int k = idx >> 5, vv = idx & 31;
    rpT[k][vv] = pack2u_(rimp_W[(size_t)vv*128 + 2*k], rimp_W[(size_t)vv*128 + 2*k+1]);
  }
  const float4* F4 = (const float4*)(fuse_W + (size_t)v*64 + 32);
  float fconst = 0.f;
  if (!half){
    fconst = fuse_b[v];
    #pragma unroll
    for (int q=0;q<8;q++){
      const float4 fw = *(const float4*)(fuse_W + (size_t)v*64 + 4*q);
      fconst += (fw.x+fw.y)+(fw.z+fw.w);
    }
  }
  const float rbias = rimp_b[v];
  __syncthreads();
  const int NOCT = (NB*NT)/8;
  for (int oc = blockIdx.x; oc < NOCT; oc += gridDim.x){
    const size_t base = (size_t)oc*8;
    __syncthreads();
    if (tid < 256){
      const float4 hv = ((const float4*)(hidden + base*128))[tid];
      const int row = tid >> 5;
      const int w0 = (tid & 31) << 1;
      hrowp[row][w0]   = pack2u_(hv.x, hv.y);
      hrowp[row][w0+1] = pack2u_(hv.z, hv.w);
    }
    __syncthreads();
    const size_t r = base + grp;
    float a = half ? 0.f : rbias;
    {
      const uint4* hp4 = (const uint4*)&hrowp[grp][half*32];
      #pragma unroll
      for (int c4=0;c4<8;c4++){
        const uint4 H = hp4[c4];
        a = dot2u_(H.x, rpT[half*32 + 4*c4][v],     a);
        a = dot2u_(H.y, rpT[half*32 + 4*c4 + 1][v], a);
        a = dot2u_(H.z, rpT[half*32 + 4*c4 + 2][v], a);
        a = dot2u_(H.w, rpT[half*32 + 4*c4 + 3][v], a);
      }
    }
    if (half){
      rpart[grp][v] = a;
      const float* mrow = masks + r*32;
      float m0=0,m1=0,m2=0,m3=0;
      #pragma unroll
      for (int q=0;q<8;q++){
        const float4 mv = *(const float4*)(mrow + 4*q);
        const float4 fv = F4[q];
        m0 = fmaf(mv.x, fv.x, m0); m1 = fmaf(mv.y, fv.y, m1);
        m2 = fmaf(mv.z, fv.z, m2); m3 = fmaf(mv.w, fv.w, m3);
      }
      bpart[grp][v] = (m0+m1)+(m2+m3);
    }
    __syncthreads();
    if (!half){
      const int bb = (int)(r >> 9);
      const int t  = (int)(r & 511);
      const int len = lengths[bb];
      const float rimp = a + rpart[grp][v];
      const float beta = sigmoidf_(fconst + bpart[grp][v]);
      const float fi = feat_imp[r*32+v];
      const float m  = masks[r*32+v];
      const float val= values[r*32+v];
      const float fz = beta*fi + (1.0f-beta)*rimp;
      const float o = m*val + (1.0f-m)*fz;
      out[r*32+v] = (t < len) ? o : 0.0f;
    }
  }
}

extern "C" void kernel_launch(void* const* d_in, const int* in_sizes, int n_in,
                              void* d_out, int out_size, void* d_ws, size_t ws_size,
                              hipStream_t stream) {
  const float* values   = (const float*)d_in[0];
  const float* masks    = (const float*)d_in[1];
  const float* rain_f   = (const float*)d_in[2];
  const float* rain_b   = (const float*)d_in[3];
  const float* cmlp_W1  = (const float*)d_in[4];
  const float* cmlp_b1  = (const float*)d_in[5];
  const float* cmlp_W2  = (const float*)d_in[6];
  const float* cmlp_b2  = (const float*)d_in[7];
  const float* gru_Wih  = (const float*)d_in[8];
  const float* gru_Whh  = (const float*)d_in[9];
  const float* gru_bih  = (const float*)d_in[10];
  const float* gru_bhh  = (const float*)d_in[11];
  const float* init_W   = (const float*)d_in[12];
  const float* init_b   = (const float*)d_in[13];
  const float* lstmf_Wih= (const float*)d_in[14];
  const float* lstmf_Whh= (const float*)d_in[15];
  const float* lstmf_bih= (const float*)d_in[16];
  const float* lstmf_bhh= (const float*)d_in[17];
  const float* lstmb_Wih= (const float*)d_in[18];
  const float* lstmb_Whh= (const float*)d_in[19];
  const float* lstmb_bih= (const float*)d_in[20];
  const float* lstmb_bhh= (const float*)d_in[21];
  const float* rimp_W   = (const float*)d_in[22];
  const float* rimp_b   = (const float*)d_in[23];
  const float* feat_W   = (const float*)d_in[24];
  const float* feat_b   = (const float*)d_in[25];
  const float* nl1_W    = (const float*)d_in[26];
  const float* nl1_b    = (const float*)d_in[27];
  const float* nl2_W    = (const float*)d_in[28];
  const float* nl2_b    = (const float*)d_in[29];
  const float* fuse_W   = (const float*)d_in[30];
  const float* fuse_b   = (const float*)d_in[31];
  const int*   lengths  = (const int*)d_in[32];
  float* out = (float*)d_out;

  float* ws       = (float*)d_ws;
  float* x_comp   = ws;                                   // B*T*V
  float* stats    = x_comp + (size_t)NB*NT*NV;            // B*97
  float* ctx      = stats + NB*97;                        // B*64
  float* h0       = ctx + NB*64;                          // B*128
  float* c0      = h0 + NB*128;                           // B*128
  float* cgF      = c0 + NB*128;                          // B*256
  float* cgB      = cgF + NB*256;                         // B*256
  float* hidden   = cgB + NB*256;                         // B*T*128
  float* feat_imp = hidden + (size_t)NB*NT*128;           // B*T*V
  unsigned short* gig = (unsigned short*)(feat_imp + (size_t)NB*NT*NV); // B*T*96 f16
  // total ~127 MB

  k_pre<<<NB + 2048, 256, 0, stream>>>(values, masks, rain_f, rain_b, lengths,
                                       gru_Wih, gru_bih, x_comp, stats, gig);
  k_gru_cmlp<<<2*NB, 64, 0, stream>>>(gig, lengths, gru_Whh, gru_bhh,
                                      stats, cmlp_W1, cmlp_b1, cmlp_W2, cmlp_b2, ctx);
  k_init<<<NB, 256, 0, stream>>>(ctx, init_W, init_b,
                                 lstmf_Wih, lstmf_bih, lstmf_bhh,
                                 lstmb_Wih, lstmb_bih, lstmb_bhh,
                                 h0, c0, cgF, cgB, hidden);
  dim3 lgrid(NB, 3);
  k_lstm_feat<<<lgrid, 256, 0, stream>>>(x_comp, masks,
                                         lstmf_Wih, lstmf_Whh, lstmb_Wih, lstmb_Whh,
                                         cgF, cgB, h0, c0, lengths, hidden,
                                         feat_W, feat_b, nl1_W, nl1_b, nl2_W, nl2_b, feat_imp);
  k_final<<<2048, 512, 0, stream>>>(values, masks, feat_imp, hidden,
                                    rimp_W, rimp_b, fuse_W, fuse_b, lengths, out);
}

// Round 23
// 867.962 us; speedup vs baseline: 1.2541x; 1.1157x over previous
//
#include <hip/hip_runtime.h>
#include <cstddef>
#include <cstdint>

constexpr int NB = 256;
constexpr int NT = 512;
constexpr int NV = 32;

typedef _Float16 h2_t __attribute__((ext_vector_type(2)));
typedef _Float16 f16x8 __attribute__((ext_vector_type(8)));
typedef float f32x4 __attribute__((ext_vector_type(4)));

__device__ __forceinline__ float sigmoidf_(float x){ return 1.0f/(1.0f+__expf(-x)); }
__device__ __forceinline__ float tanhf_(float x){ return 1.0f - 2.0f/(__expf(2.0f*x)+1.0f); }

__device__ __forceinline__ uint32_t pack2u_(float a, float b){
  h2_t r; r.x=(_Float16)a; r.y=(_Float16)b; return __builtin_bit_cast(uint32_t, r);
}
__device__ __forceinline__ float dot2u_(uint32_t u, uint32_t w, float c){
#if __has_builtin(__builtin_amdgcn_fdot2)
  return __builtin_amdgcn_fdot2(__builtin_bit_cast(h2_t,u), __builtin_bit_cast(h2_t,w), c, false);
#else
  h2_t a=__builtin_bit_cast(h2_t,u), b2=__builtin_bit_cast(h2_t,w);
  return c + (float)a.x*(float)b2.x + (float)a.y*(float)b2.y;
#endif
}
__device__ __forceinline__ float h2f_(unsigned short u){
  _Float16 hv = __builtin_bit_cast(_Float16, u); return (float)hv;
}
__device__ __forceinline__ unsigned short f2h_(float a){
  _Float16 hv = (_Float16)a; return __builtin_bit_cast(unsigned short, hv);
}

// ---------------- fused: stats+x_comp (blocks 0..255)  |  gigru w/ inline x (blocks 256..2303) ----------------
__global__ __launch_bounds__(256) void k_pre(
    const float* __restrict__ values, const float* __restrict__ masks,
    const float* __restrict__ rain_f, const float* __restrict__ rain_b,
    const int* __restrict__ lengths,
    const float* __restrict__ Wih, const float* __restrict__ bih,
    float* __restrict__ x_comp, float* __restrict__ stats,
    unsigned short* __restrict__ gig)
{
  __shared__ float red[4][8][32];
  __shared__ uint32_t WT[48][98];
  __shared__ __align__(16) uint32_t us[16][48];
  const int tid = threadIdx.x;
  if (blockIdx.x < NB){
    // ---------- stats role ----------
    const int b = blockIdx.x;
    const int v = tid & 31;
    const int g = tid >> 5;
    const int len = lengths[b];
    const float* vb = values + (size_t)b*NT*NV;
    const float* mb = masks  + (size_t)b*NT*NV;
    float* xb = x_comp + (size_t)b*NT*NV;
    float s_m=0.f, s_mv=0.f, s_v=0.f, s_v2=0.f;
    for (int t=g; t<NT; t+=8){
      float val = vb[t*NV+v];
      float m   = mb[t*NV+v];
      float xp  = (t==0) ? vb[v] : vb[(t-1)*NV+v];
      float pm  = (t<len) ? 1.0f : 0.0f;
      xb[t*NV+v] = (m*val + (1.0f-m)*xp)*pm;
      s_m += m; s_mv += m*val; s_v += val; s_v2 += val*val;
    }
    red[0][g][v]=s_m; red[1][g][v]=s_mv; red[2][g][v]=s_v; red[3][g][v]=s_v2;
    __syncthreads();
    if (g==0){
      float a0=0,a1=0,a2=0,a3=0;
      #pragma unroll
      for(int i=0;i<8;i++){ a0+=red[0][i][v]; a1+=red[1][i][v]; a2+=red[2][i][v]; a3+=red[3][i][v]; }
      float msum = fmaxf(a0, 1.0f);
      float mean = a1/msum;
      float dss  = a3 - 2.0f*mean*a2 + (float)NT*mean*mean;
      float var  = (msum > 1.0f) ? dss/(msum-1.0f) : 0.0f;
      float sd   = sqrtf(fmaxf(var, 0.0f));
      float miss = 1.0f - a0 / fmaxf((float)len, 1.0f);
      float* st = stats + b*97;
      if (v==0) st[0] = (float)len;
      st[1+v]=mean; st[33+v]=sd; st[65+v]=miss;
    }
    return;
  }
  // ---------- gigru role (x_comp recomputed inline; no dependency on stats role) ----------
  const int bid = blockIdx.x - NB;   // 0..2047
  for (int idx = tid; idx < 48*96; idx += 256){
    const int k = idx / 96, col = idx - k*96;
    WT[k][col] = pack2u_(Wih[(size_t)col*96 + 2*k], Wih[(size_t)col*96 + 2*k + 1]);
  }
  const bool act = (tid < 192);
  const int grp = (tid >= 96) ? 1 : 0;
  const int col = tid - grp*96;
  const float bias = act ? bih[col] : 0.f;
  __syncthreads();
  const int NR = NB*NT;
  for (int r0 = bid*16; r0 < NR; r0 += 2048*16){
    __syncthreads();
    for (int idx = tid; idx < 16*48; idx += 256){
      const int r = idx / 48, w = idx - r*48;
      const size_t row = (size_t)r0 + r;
      const int bb = (int)(row >> 9), t = (int)(row & 511);
      const int len = lengths[bb];
      const float pm = (t < len) ? 1.0f : 0.0f;
      float vz[2];
      #pragma unroll
      for (int z=0; z<2; z++){
        const int i = 2*w + z;
        float a;
        if (i < 32){
          const float val = values[row*32 + i];
          const float m   = masks[row*32 + i];
          const float xp  = (t==0) ? values[((size_t)bb*NT)*32 + i] : values[(row-1)*32 + i];
          a = (m*val + (1.0f-m)*xp)*pm;
        } else if (i < 64){
          a = rain_f[row*32 + i - 32];
        } else {
          a = rain_b[row*32 + i - 64];
        }
        vz[z] = a;
      }
      us[r][w] = pack2u_(vz[0], vz[1]);
    }
    __syncthreads();
    if (act){
      #pragma unroll
      for (int r=0;r<8;r++){
        const int rr = grp*8 + r;
        const uint4* U = (const uint4*)us[rr];
        float acc = bias;
        #pragma unroll
        for (int k4=0;k4<12;k4++){
          const uint4 u4 = U[k4];
          acc = dot2u_(u4.x, WT[4*k4][col],   acc);
          acc = dot2u_(u4.y, WT[4*k4+1][col], acc);
          acc = dot2u_(u4.z, WT[4*k4+2][col], acc);
          acc = dot2u_(u4.w, WT[4*k4+3][col], acc);
        }
        gig[((size_t)r0+rr)*96 + col] = f2h_(acc);
      }
    }
  }
}

// ---------------- fused: GRU scan (blocks 0..255) | context MLP (blocks 256..511), 64 thr ----------------
// GRU role: 4-deep software-pipelined gig prefetch (raw ushort regs, convert at use).
__global__ __launch_bounds__(64,4) void k_gru_cmlp(
    const unsigned short* __restrict__ gig, const int* __restrict__ lengths,
    const float* __restrict__ Whh, const float* __restrict__ bhh,
    const float* __restrict__ stats,
    const float* __restrict__ W1, const float* __restrict__ b1,
    const float* __restrict__ W2, const float* __restrict__ b2,
    float* __restrict__ ctx)
{
  __shared__ __align__(16) _Float16 hbuf[2][32];
  __shared__ float st[97];
  __shared__ float hm[64];
  const int l = threadIdx.x;
  if (blockIdx.x >= NB){
    // ---------- cmlp role ----------
    const int b = blockIdx.x - NB;
    const int j = l;
    for (int k=j; k<97; k+=64) st[k] = stats[b*97+k];
    __syncthreads();
    float a0=b1[j], a1=0.f, a2=0.f, a3=0.f;
    #pragma unroll
    for (int k=0; k<96; k+=4){
      a0 += st[k]*W1[j*97+k];     a1 += st[k+1]*W1[j*97+k+1];
      a2 += st[k+2]*W1[j*97+k+2]; a3 += st[k+3]*W1[j*97+k+3];
    }
    a0 += st[96]*W1[j*97+96];
    hm[j] = fmaxf((a0+a1)+(a2+a3), 0.0f);
    __syncthreads();
    if (j < 32){
      float c0_=b2[j], c1=0.f, c2=0.f, c3=0.f;
      #pragma unroll
      for (int k=0;k<64;k+=4){
        c0_ += hm[k]*W2[j*64+k];    c1 += hm[k+1]*W2[j*64+k+1];
        c2 += hm[k+2]*W2[j*64+k+2]; c3 += hm[k+3]*W2[j*64+k+3];
      }
      ctx[b*64+j] = (c0_+c1)+(c2+c3);
    }
    return;
  }
  // ---------- gru role (4-deep pipelined) ----------
  const int b = blockIdx.x;
  const int arow = l & 15, ak = (l >> 4) * 8;
  const int rg = l >> 4, j4 = l & 3;
  const int crow = rg * 4;
  const int e0 = crow + j4, e1 = 16 + e0;
  const bool writer = ((l & 15) >> 2) == 0;
  f16x8 A0, A1, A2, A3, A4, A5;
  #define LDA(dst, mt) { const float* p_ = Whh + (size_t)((mt)*16 + arow)*32 + ak; \
    f16x8 t_; _Pragma("unroll") for (int e_=0;e_<8;++e_) t_[e_] = (_Float16)p_[e_]; dst = t_; }
  LDA(A0,0) LDA(A1,1) LDA(A2,2) LDA(A3,3) LDA(A4,4) LDA(A5,5)
  #undef LDA
  f32x4 bb0, bb1, bb2, bb3, bb4, bb5;
  #pragma unroll
  for (int j=0;j<4;j++){
    bb0[j] = bhh[0*16 + crow + j]; bb1[j] = bhh[1*16 + crow + j];
    bb2[j] = bhh[2*16 + crow + j]; bb3[j] = bhh[3*16 + crow + j];
    bb4[j] = bhh[4*16 + crow + j]; bb5[j] = bhh[5*16 + crow + j];
  }
  asm volatile("" ::: "memory");
  int len = lengths[b]; if (len > NT) len = NT;
  float h0v = 0.f, h1v = 0.f;
  if (l < 32) hbuf[0][l] = (_Float16)0.f;
  const unsigned short* gp = gig + (size_t)b*NT*96;
  unsigned short uA0=0,uA1=0,uA2=0,uA3=0,uA4=0,uA5=0;
  unsigned short uB0=0,uB1=0,uB2=0,uB3=0,uB4=0,uB5=0;
  unsigned short uC0=0,uC1=0,uC2=0,uC3=0,uC4=0,uC5=0;
  unsigned short uD0=0,uD1=0,uD2=0,uD3=0,uD4=0,uD5=0;
  #define PF(tq, U0,U1,U2,U3,U4,U5) { const int tq_ = (tq); \
    if (tq_ < len){ const unsigned short* gq_ = gp + (size_t)tq_*96; \
      U0 = gq_[e0]; U1 = gq_[32+e0]; U2 = gq_[64+e0]; \
      U3 = gq_[e1]; U4 = gq_[32+e1]; U5 = gq_[64+e1]; } }
  PF(0, uA0,uA1,uA2,uA3,uA4,uA5)
  PF(1, uB0,uB1,uB2,uB3,uB4,uB5)
  PF(2, uC0,uC1,uC2,uC3,uC4,uC5)
  PF(3, uD0,uD1,uD2,uD3,uD4,uD5)
  __syncthreads();
  #define STEP(tt, U0,U1,U2,U3,U4,U5) { const int t_ = (tt); \
    if (t_ < len){ \
      const int cur_ = t_ & 1; \
      const f16x8 bh_ = *(const f16x8*)&hbuf[cur_][ak]; \
      f32x4 a0 = bb0, a1 = bb1, a2 = bb2, a3 = bb3, a4 = bb4, a5 = bb5; \
      a0 = __builtin_amdgcn_mfma_f32_16x16x32_f16(A0, bh_, a0, 0, 0, 0); \
      a1 = __builtin_amdgcn_mfma_f32_16x16x32_f16(A1, bh_, a1, 0, 0, 0); \
      a2 = __builtin_amdgcn_mfma_f32_16x16x32_f16(A2, bh_, a2, 0, 0, 0); \
      a3 = __builtin_amdgcn_mfma_f32_16x16x32_f16(A3, bh_, a3, 0, 0, 0); \
      a4 = __builtin_amdgcn_mfma_f32_16x16x32_f16(A4, bh_, a4, 0, 0, 0); \
      a5 = __builtin_amdgcn_mfma_f32_16x16x32_f16(A5, bh_, a5, 0, 0, 0); \
      const float r0_ = sigmoidf_(h2f_(U0) + a0[j4]); \
      const float z0_ = sigmoidf_(h2f_(U1) + a2[j4]); \
      const float n0_ = tanhf_(h2f_(U2) + r0_*a4[j4]); \
      h0v = (1.0f - z0_)*n0_ + z0_*h0v; \
      const float r1_ = sigmoidf_(h2f_(U3) + a1[j4]); \
      const float z1_ = sigmoidf_(h2f_(U4) + a3[j4]); \
      const float n1_ = tanhf_(h2f_(U5) + r1_*a5[j4]); \
      h1v = (1.0f - z1_)*n1_ + z1_*h1v; \
      if (writer){ \
        hbuf[cur_^1][e0] = (_Float16)h0v; \
        hbuf[cur_^1][e1] = (_Float16)h1v; \
      } \
      __syncthreads(); } }
  for (int t=0; t<len; t+=4){
    STEP(t,   uA0,uA1,uA2,uA3,uA4,uA5)  PF(t+4, uA0,uA1,uA2,uA3,uA4,uA5)
    STEP(t+1, uB0,uB1,uB2,uB3,uB4,uB5)  PF(t+5, uB0,uB1,uB2,uB3,uB4,uB5)
    STEP(t+2, uC0,uC1,uC2,uC3,uC4,uC5)  PF(t+6, uC0,uC1,uC2,uC3,uC4,uC5)
    STEP(t+3, uD0,uD1,uD2,uD3,uD4,uD5)  PF(t+7, uD0,uD1,uD2,uD3,uD4,uD5)
  }
  #undef STEP
  #undef PF
  if (writer){
    ctx[b*64 + 32 + e0] = h0v;
    ctx[b*64 + 32 + e1] = h1v;
  }
}

// ---------------- init: h0/c0, ctx-part of LSTM gates, hidden seeds ----------------
__global__ __launch_bounds__(256) void k_init(
    const float* __restrict__ ctx,
    const float* __restrict__ initW, const float* __restrict__ initb,
    const float* __restrict__ WihF, const float* __restrict__ bihF, const float* __restrict__ bhhF,
    const float* __restrict__ WihB, const float* __restrict__ bihB, const float* __restrict__ bhhB,
    float* __restrict__ h0, float* __restrict__ c0,
    float* __restrict__ cgF, float* __restrict__ cgB,
    float* __restrict__ hidden)
{
  const int b = blockIdx.x;
  const int j = threadIdx.x;
  __shared__ __align__(16) float cv[64];
  if (j < 64) cv[j] = ctx[b*64+j];
  __syncthreads();
  {
    float4 f = {bihF[j]+bhhF[j], 0.f, 0.f, 0.f};
    float4 g = {bihB[j]+bhhB[j], 0.f, 0.f, 0.f};
    #pragma unroll
    for (int q=0;q<16;q++){
      const float4 cvv = *(const float4*)&cv[4*q];
      const float4 wf = *(const float4*)(WihF + (size_t)j*128 + 64 + 4*q);
      const float4 wb = *(const float4*)(WihB + (size_t)j*128 + 64 + 4*q);
      f.x += cvv.x*wf.x; f.y += cvv.y*wf.y; f.z += cvv.z*wf.z; f.w += cvv.w*wf.w;
      g.x += cvv.x*wb.x; g.y += cvv.y*wb.y; g.z += cvv.z*wb.z; g.w += cvv.w*wb.w;
    }
    cgF[b*256+j] = (f.x+f.y)+(f.z+f.w);
    cgB[b*256+j] = (g.x+g.y)+(g.z+g.w);
  }
  if (j < 128){
    float4 a = {initb[j], 0.f, 0.f, 0.f};
    #pragma unroll
    for (int q=0;q<16;q++){
      const float4 cvv = *(const float4*)&cv[4*q];
      const float4 w  = *(const float4*)(initW + (size_t)j*64 + 4*q);
      a.x += cvv.x*w.x; a.y += cvv.y*w.y; a.z += cvv.z*w.z; a.w += cvv.w*w.w;
    }
    float hv = (a.x+a.y)+(a.z+a.w);
    h0[b*128+j] = hv;
    c0[b*128+j] = tanhf_(hv);
    if (j < 64) hidden[(size_t)b*NT*128 + j] = hv;                                // fwd seed t=0
    else        hidden[(size_t)b*NT*128 + (size_t)(NT-1)*128 + 64 + (j-64)] = hv; // bwd seed t=T-1
  }
}

// ---------------- fused LSTM scan + feature-regression (r20-proven) ----------------
__global__ __launch_bounds__(256,2) void k_lstm_feat(
    const float* __restrict__ x_comp, const float* __restrict__ masks,
    const float* __restrict__ WihF, const float* __restrict__ WhhF,
    const float* __restrict__ WihB, const float* __restrict__ WhhB,
    const float* __restrict__ cgF, const float* __restrict__ cgB,
    const float* __restrict__ h0, const float* __restrict__ c0,
    const int* __restrict__ lengths,
    float* __restrict__ hidden,
    const float* __restrict__ feat_W, const float* __restrict__ feat_b,
    const float* __restrict__ nl1_W, const float* __restrict__ nl1_b,
    const float* __restrict__ nl2_W, const float* __restrict__ nl2_b,
    float* __restrict__ feat_imp)
{
  __shared__ __align__(16) _Float16 ubuf[2][64];
  __shared__ __align__(16) _Float16 hbuf[2][64];
  __shared__ __align__(16) _Float16 xbuf[16*32];
  __shared__ __align__(16) _Float16 hidb[32*16*40];     // stride 40 (padded)
  __shared__ __align__(16) float fbl[1024];
  __shared__ float fout[16*33];
  const int tid = threadIdx.x;
  if (blockIdx.y < 2){
    const int b = blockIdx.x, dir = blockIdx.y;
    const int l = tid & 63, wv = tid >> 6;
    const int eg = wv * 16;
    const int arow = l & 15, ak = (l >> 4) * 8;
    const int rowg = l >> 4;
    const int j4 = l & 3;
    const int elem = eg + rowg*4 + j4;
    const bool writer = ((l & 15) >> 2) == 0;
    const float* Wih = dir ? WihB : WihF;
    const float* Whh = dir ? WhhB : WhhF;
    f16x8 X0a,X0b,X1a,X1b,X2a,X2b,X3a,X3b;
    f16x8 H0a,H0b,H1a,H1b,H2a,H2b,H3a,H3b;
    #define LDFRAG(dst, base, ld, row, kk) { \
      const float* p_ = (base) + (size_t)(row)*(ld) + (kk); \
      const float4 v0_ = *(const float4*)p_; const float4 v1_ = *(const float4*)(p_+4); \
      f16x8 t_; t_[0]=(_Float16)v0_.x; t_[1]=(_Float16)v0_.y; t_[2]=(_Float16)v0_.z; t_[3]=(_Float16)v0_.w; \
      t_[4]=(_Float16)v1_.x; t_[5]=(_Float16)v1_.y; t_[6]=(_Float16)v1_.z; t_[7]=(_Float16)v1_.w; dst = t_; }
    LDFRAG(X0a, Wih, 128, 0*64+eg+arow, ak)    LDFRAG(X0b, Wih, 128, 0*64+eg+arow, 32+ak)
    LDFRAG(X1a, Wih, 128, 1*64+eg+arow, ak)    LDFRAG(X1b, Wih, 128, 1*64+eg+arow, 32+ak)
    LDFRAG(X2a, Wih, 128, 2*64+eg+arow, ak)    LDFRAG(X2b, Wih, 128, 2*64+eg+arow, 32+ak)
    LDFRAG(X3a, Wih, 128, 3*64+eg+arow, ak)    LDFRAG(X3b, Wih, 128, 3*64+eg+arow, 32+ak)
    LDFRAG(H0a, Whh, 64,  0*64+eg+arow, ak)    LDFRAG(H0b, Whh, 64,  0*64+eg+arow, 32+ak)
    LDFRAG(H1a, Whh, 64,  1*64+eg+arow, ak)    LDFRAG(H1b, Whh, 64,  1*64+eg+arow, 32+ak)
    LDFRAG(H2a, Whh, 64,  2*64+eg+arow, ak)    LDFRAG(H2b, Whh, 64,  2*64+eg+arow, 32+ak)
    LDFRAG(H3a, Whh, 64,  3*64+eg+arow, ak)    LDFRAG(H3b, Whh, 64,  3*64+eg+arow, 32+ak)
    #undef LDFRAG
    const float* cgp = (dir ? cgB : cgF) + (size_t)b*256;
    const int crow = rowg * 4;
    const f32x4 cgi = *(const f32x4*)(cgp + 0*64 + eg + crow);
    const f32x4 cgf = *(const f32x4*)(cgp + 1*64 + eg + crow);
    const f32x4 cgg = *(const f32x4*)(cgp + 2*64 + eg + crow);
    const f32x4 cgo = *(const f32x4*)(cgp + 3*64 + eg + crow);
    asm volatile("" ::: "memory");
    const int len = lengths[b];
    int nsteps = NT-1;
    if (dir == 0){ int e = len-1; if (e<0) e=0; if (e<nsteps) nsteps = e; }
    const float* xc = x_comp + (size_t)b*NT*NV;
    const float* mk = masks  + (size_t)b*NT*NV;
    float* hout = hidden + (size_t)b*NT*128 + dir*64;
    float cst = c0[(size_t)b*128 + dir*64 + elem];
    if (tid < 64) hbuf[0][tid] = (_Float16)h0[(size_t)b*128 + dir*64 + tid];
    if (tid >= 64 && tid < 96 && nsteps > 0){
      const int u = tid - 64;
      const int t0 = dir ? NT-1 : 0;
      const float2 v = (u<16) ? *(const float2*)(xc + t0*NV + 2*u)
                              : *(const float2*)(mk + t0*NV + 2*(u-16));
      ubuf[0][2*u] = (_Float16)v.x; ubuf[0][2*u+1] = (_Float16)v.y;
    }
    __syncthreads();
    for (int s=0; s<nsteps; ++s){
      const int cur = s & 1;
      float2 pre = {0.f, 0.f};
      const bool dopf = (tid >= 64 && tid < 96 && s+1 < nsteps);
      if (dopf){
        const int u = tid - 64;
        const int tn = dir ? (NT-2-s) : (s+1);
        pre = (u<16) ? *(const float2*)(xc + tn*NV + 2*u)
                     : *(const float2*)(mk + tn*NV + 2*(u-16));
      }
      const f16x8 bu0 = *(const f16x8*)&ubuf[cur][ak];
      const f16x8 bu1 = *(const f16x8*)&ubuf[cur][32+ak];
      const f16x8 bh0 = *(const f16x8*)&hbuf[cur][ak];
      const f16x8 bh1 = *(const f16x8*)&hbuf[cur][32+ak];
      f32x4 ai = cgi, af = cgf, ag = cgg, ao = cgo;
      ai = __builtin_amdgcn_mfma_f32_16x16x32_f16(X0a, bu0, ai, 0, 0, 0);
      af = __builtin_amdgcn_mfma_f32_16x16x32_f16(X1a, bu0, af, 0, 0, 0);
      ag = __builtin_amdgcn_mfma_f32_16x16x32_f16(X2a, bu0, ag, 0, 0, 0);
      ao = __builtin_amdgcn_mfma_f32_16x16x32_f16(X3a, bu0, ao, 0, 0, 0);
      ai = __builtin_amdgcn_mfma_f32_16x16x32_f16(X0b, bu1, ai, 0, 0, 0);
      af = __builtin_amdgcn_mfma_f32_16x16x32_f16(X1b, bu1, af, 0, 0, 0);
      ag = __builtin_amdgcn_mfma_f32_16x16x32_f16(X2b, bu1, ag, 0, 0, 0);
      ao = __builtin_amdgcn_mfma_f32_16x16x32_f16(X3b, bu1, ao, 0, 0, 0);
      ai = __builtin_amdgcn_mfma_f32_16x16x32_f16(H0a, bh0, ai, 0, 0, 0);
      af = __builtin_amdgcn_mfma_f32_16x16x32_f16(H1a, bh0, af, 0, 0, 0);
      ag = __builtin_amdgcn_mfma_f32_16x16x32_f16(H2a, bh0, ag, 0, 0, 0);
      ao = __builtin_amdgcn_mfma_f32_16x16x32_f16(H3a, bh0, ao, 0, 0, 0);
      ai = __builtin_amdgcn_mfma_f32_16x16x32_f16(H0b, bh1, ai, 0, 0, 0);
      af = __builtin_amdgcn_mfma_f32_16x16x32_f16(H1b, bh1, af, 0, 0, 0);
      ag = __builtin_amdgcn_mfma_f32_16x16x32_f16(H2b, bh1, ag, 0, 0, 0);
      ao = __builtin_amdgcn_mfma_f32_16x16x32_f16(H3b, bh1, ao, 0, 0, 0);
      const float gi = ai[j4], gf = af[j4], gg = ag[j4], go = ao[j4];
      cst = sigmoidf_(gf)*cst + sigmoidf_(gi)*tanhf_(gg);
      const float hh = sigmoidf_(go)*tanhf_(cst);
      if (writer){
        hbuf[cur^1][elem] = (_Float16)hh;
        const int outt = dir ? (NT-2-s) : (s+1);
        hout[(size_t)outt*128 + elem] = hh;
      }
      if (dopf){
        const int u = tid - 64;
        ubuf[cur^1][2*u]   = (_Float16)pre.x;
        ubuf[cur^1][2*u+1] = (_Float16)pre.y;
      }
      __syncthreads();
    }
    return;
  }
  // ================= feat path (4 waves, padded hidb) =================
  {
    const int l = tid & 63, wv = tid >> 6;         // wv 0..3
    const int fr = l >> 4, fc = l & 15;
    const int ak = fr * 8;
    f16x8 WA[16];
    #pragma unroll
    for (int q=0;q<16;q++){
      const int m_ = (wv*16 + q)*16 + fc;
      const int i_ = m_ >> 5;
      const float* s_ = feat_W + (size_t)m_*32 + ak;
      f16x8 t_;
      #pragma unroll
      for (int e_=0; e_<8; ++e_){
        float w_ = s_[e_];
        if (ak + e_ == i_) w_ = 0.f;
        t_[e_] = (_Float16)w_;
      }
      WA[q] = t_;
    }
    f16x8 NA0, NA1;
    {
      f16x8 t0, t1;
      #pragma unroll
      for (int e=0;e<8;e++){
        t0[e] = (_Float16)nl1_W[(fc)*32 + ak + e];
        t1[e] = (_Float16)nl1_W[(16 + fc)*32 + ak + e];
      }
      NA0 = t0; NA1 = t1;
    }
    f32x4 n1b0, n1b1;
    float n2w0[4], n2w1[4];
    #pragma unroll
    for (int j=0;j<4;j++){
      n1b0[j] = nl1_b[fr*4+j];
      n1b1[j] = nl1_b[16 + fr*4+j];
      n2w0[j] = nl2_W[fr*4+j];
      n2w1[j] = nl2_W[16 + fr*4+j];
    }
    const float n2b = nl2_b[0];
    for (int idx = tid; idx < 1024; idx += 256) fbl[idx] = feat_b[idx];
    asm volatile("" ::: "memory");
    const int NG = (NB*NT)/16;
    for (int g = blockIdx.x; g < NG; g += 256){
      const size_t r0 = (size_t)g*16;
      __syncthreads();
      {
        const int n0 = tid >> 4, v2 = (tid & 15)*2;   // 2 elems/thread
        const float2 xv = *(const float2*)&x_comp[(r0+n0)*32 + v2];
        xbuf[n0*32+v2]   = (_Float16)xv.x;
        xbuf[n0*32+v2+1] = (_Float16)xv.y;
      }
      __syncthreads();
      const f16x8 xB = *(const f16x8*)&xbuf[fc*32 + ak];
      #pragma unroll
      for (int q=0;q<16;q++){
        const int mt = wv*16 + q;
        f32x4 acc = {0.f,0.f,0.f,0.f};
        acc = __builtin_amdgcn_mfma_f32_16x16x32_f16(WA[q], xB, acc, 0, 0, 0);
        const int mbase = mt*16 + fr*4;
        const f32x4 fb4 = *(const f32x4*)&fbl[mbase];
        #pragma unroll
        for (int jj=0;jj<4;jj+=2){
          const int m0_ = mbase + jj;
          const int i_ = m0_ >> 5, h_ = m0_ & 31;
          const float v0_ = fmaxf(acc[jj]   + fb4[jj],   0.f);
          const float v1_ = fmaxf(acc[jj+1] + fb4[jj+1], 0.f);
          h2_t p; p.x = (_Float16)v0_; p.y = (_Float16)v1_;
          *(h2_t*)&hidb[(i_*16+fc)*40 + h_] = p;
        }
      }
      __syncthreads();
      float outv[8];
      #pragma unroll
      for (int q=0;q<8;q++){
        const int nt = wv*8 + q;
        const f16x8 hB = *(const f16x8*)&hidb[(nt*16+fc)*40 + ak];
        f32x4 z0 = n1b0, z1 = n1b1;
        z0 = __builtin_amdgcn_mfma_f32_16x16x32_f16(NA0, hB, z0, 0, 0, 0);
        z1 = __builtin_amdgcn_mfma_f32_16x16x32_f16(NA1, hB, z1, 0, 0, 0);
        float s = 0.f;
        #pragma unroll
        for (int j=0;j<4;j++){
          s += fmaxf(z0[j], 0.f)*n2w0[j];
          s += fmaxf(z1[j], 0.f)*n2w1[j];
        }
        s += __shfl_xor(s, 16);
        s += __shfl_xor(s, 32);
        outv[q] = s;
      }
      if (fr == 0){
        #pragma unroll
        for (int q=0;q<8;q++) fout[fc*33 + wv*8 + q] = outv[q] + n2b;
      }
      __syncthreads();
      feat_imp[r0*32 + tid]       = fout[(tid>>5)*33 + (tid&31)];
      feat_imp[r0*32 + 256 + tid] = fout[((tid+256)>>5)*33 + (tid&31)];
    }
  }
}

// ---------------- rnn_imp GEMM + fuse + final: LDS f16 rimp ----------------
__global__ __launch_bounds__(512) void k_final(
    const float* __restrict__ values, const float* __restrict__ masks,
    const float* __restrict__ feat_imp, const float* __restrict__ hidden,
    const float* __restrict__ rimp_W, const float* __restrict__ rimp_b,
    const float* __restrict__ fuse_W, const float* __restrict__ fuse_b,
    const int* __restrict__ lengths, float* __restrict__ out)
{
  const int tid = threadIdx.x;
  const int v = tid & 31;
  const int grp = (tid >> 5) & 7;
  const int half = tid >> 8;
  __shared__ uint32_t rpT[64][32];
  __shared__ __align__(16) uint32_t hrowp[8][64];
  __shared__ float rpart[8][32];
  __shared__ float bpart[8][32];
  for (int idx = tid; idx < 64*32; idx += 512){
    const int k = idx >> 5, vv = idx & 31;
    rpT[k][vv] = pack2u_(rimp_W[(size_t)vv*128 + 2*k], rimp_W[(size_t)vv*128 + 2*k+1]);
  }
  const float4* F4 = (const float4*)(fuse_W + (size_t)v*64 + 32);
  float fconst = 0.f;
  if (!half){
    fconst = fuse_b[v];
    #pragma unroll
    for (int q=0;q<8;q++){
      const float4 fw = *(const float4*)(fuse_W + (size_t)v*64 + 4*q);
      fconst += (fw.x+fw.y)+(fw.z+fw.w);
    }
  }
  const float rbias = rimp_b[v];
  __syncthreads();
  const int NOCT = (NB*NT)/8;
  for (int oc = blockIdx.x; oc < NOCT; oc += gridDim.x){
    const size_t base = (size_t)oc*8;
    __syncthreads();
    if (tid < 256){
      const float4 hv = ((const float4*)(hidden + base*128))[tid];
      const int row = tid >> 5;
      const int w0 = (tid & 31) << 1;
      hrowp[row][w0]   = pack2u_(hv.x, hv.y);
      hrowp[row][w0+1] = pack2u_(hv.z, hv.w);
    }
    __syncthreads();
    const size_t r = base + grp;
    float a = half ? 0.f : rbias;
    {
      const uint4* hp4 = (const uint4*)&hrowp[grp][half*32];
      #pragma unroll
      for (int c4=0;c4<8;c4++){
        const uint4 H = hp4[c4];
        a = dot2u_(H.x, rpT[half*32 + 4*c4][v],     a);
        a = dot2u_(H.y, rpT[half*32 + 4*c4 + 1][v], a);
        a = dot2u_(H.z, rpT[half*32 + 4*c4 + 2][v], a);
        a = dot2u_(H.w, rpT[half*32 + 4*c4 + 3][v], a);
      }
    }
    if (half){
      rpart[grp][v] = a;
      const float* mrow = masks + r*32;
      float m0=0,m1=0,m2=0,m3=0;
      #pragma unroll
      for (int q=0;q<8;q++){
        const float4 mv = *(const float4*)(mrow + 4*q);
        const float4 fv = F4[q];
        m0 = fmaf(mv.x, fv.x, m0); m1 = fmaf(mv.y, fv.y, m1);
        m2 = fmaf(mv.z, fv.z, m2); m3 = fmaf(mv.w, fv.w, m3);
      }
      bpart[grp][v] = (m0+m1)+(m2+m3);
    }
    __syncthreads();
    if (!half){
      const int bb = (int)(r >> 9);
      const int t  = (int)(r & 511);
      const int len = lengths[bb];
      const float rimp = a + rpart[grp][v];
      const float beta = sigmoidf_(fconst + bpart[grp][v]);
      const float fi = feat_imp[r*32+v];
      const float m  = masks[r*32+v];
      const float val= values[r*32+v];
      const float fz = beta*fi + (1.0f-beta)*rimp;
      const float o = m*val + (1.0f-m)*fz;
      out[r*32+v] = (t < len) ? o : 0.0f;
    }
  }
}

extern "C" void kernel_launch(void* const* d_in, const int* in_sizes, int n_in,
                              void* d_out, int out_size, void* d_ws, size_t ws_size,
                              hipStream_t stream) {
  const float* values   = (const float*)d_in[0];
  const float* masks    = (const float*)d_in[1];
  const float* rain_f   = (const float*)d_in[2];
  const float* rain_b   = (const float*)d_in[3];
  const float* cmlp_W1  = (const float*)d_in[4];
  const float* cmlp_b1  = (const float*)d_in[5];
  const float* cmlp_W2  = (const float*)d_in[6];
  const float* cmlp_b2  = (const float*)d_in[7];
  const float* gru_Wih  = (const float*)d_in[8];
  const float* gru_Whh  = (const float*)d_in[9];
  const float* gru_bih  = (const float*)d_in[10];
  const float* gru_bhh  = (const float*)d_in[11];
  const float* init_W   = (const float*)d_in[12];
  const float* init_b   = (const float*)d_in[13];
  const float* lstmf_Wih= (const float*)d_in[14];
  const float* lstmf_Whh= (const float*)d_in[15];
  const float* lstmf_bih= (const float*)d_in[16];
  const float* lstmf_bhh= (const float*)d_in[17];
  const float* lstmb_Wih= (const float*)d_in[18];
  const float* lstmb_Whh= (const float*)d_in[19];
  const float* lstmb_bih= (const float*)d_in[20];
  const float* lstmb_bhh= (const float*)d_in[21];
  const float* rimp_W   = (const float*)d_in[22];
  const float* rimp_b   = (const float*)d_in[23];
  const float* feat_W   = (const float*)d_in[24];
  const float* feat_b   = (const float*)d_in[25];
  const float* nl1_W    = (const float*)d_in[26];
  const float* nl1_b    = (const float*)d_in[27];
  const float* nl2_W    = (const float*)d_in[28];
  const float* nl2_b    = (const float*)d_in[29];
  const float* fuse_W   = (const float*)d_in[30];
  const float* fuse_b   = (const float*)d_in[31];
  const int*   lengths  = (const int*)d_in[32];
  float* out = (float*)d_out;

  float* ws       = (float*)d_ws;
  float* x_comp   = ws;                                   // B*T*V
  float* stats    = x_comp + (size_t)NB*NT*NV;            // B*97
  float* ctx      = stats + NB*97;                        // B*64
  float* h0       = ctx + NB*64;                          // B*128
  float* c0      = h0 + NB*128;                           // B*128
  float* cgF      = c0 + NB*128;                          // B*256
  float* cgB      = cgF + NB*256;                         // B*256
  float* hidden   = cgB + NB*256;                         // B*T*128
  float* feat_imp = hidden + (size_t)NB*NT*128;           // B*T*V
  unsigned short* gig = (unsigned short*)(feat_imp + (size_t)NB*NT*NV); // B*T*96 f16
  // total ~127 MB

  k_pre<<<NB + 2048, 256, 0, stream>>>(values, masks, rain_f, rain_b, lengths,
                                       gru_Wih, gru_bih, x_comp, stats, gig);
  k_gru_cmlp<<<2*NB, 64, 0, stream>>>(gig, lengths, gru_Whh, gru_bhh,
                                      stats, cmlp_W1, cmlp_b1, cmlp_W2, cmlp_b2, ctx);
  k_init<<<NB, 256, 0, stream>>>(ctx, init_W, init_b,
                                 lstmf_Wih, lstmf_bih, lstmf_bhh,
                                 lstmb_Wih, lstmb_bih, lstmb_bhh,
                                 h0, c0, cgF, cgB, hidden);
  dim3 lgrid(NB, 3);
  k_lstm_feat<<<lgrid, 256, 0, stream>>>(x_comp, masks,
                                         lstmf_Wih, lstmf_Whh, lstmb_Wih, lstmb_Whh,
                                         cgF, cgB, h0, c0, lengths, hidden,
                                         feat_W, feat_b, nl1_W, nl1_b, nl2_W, nl2_b, feat_imp);
  k_final<<<2048, 512, 0, stream>>>(values, masks, feat_imp, hidden,
                                    rimp_W, rimp_b, fuse_W, fuse_b, lengths, out);
}

// Round 24
// 863.362 us; speedup vs baseline: 1.2608x; 1.0053x over previous
//
#include <hip/hip_runtime.h>
#include <cstddef>
#include <cstdint>

constexpr int NB = 256;
constexpr int NT = 512;
constexpr int NV = 32;

typedef _Float16 h2_t __attribute__((ext_vector_type(2)));
typedef _Float16 f16x8 __attribute__((ext_vector_type(8)));
typedef float f32x4 __attribute__((ext_vector_type(4)));

__device__ __forceinline__ float sigmoidf_(float x){ return 1.0f/(1.0f+__expf(-x)); }
__device__ __forceinline__ float tanhf_(float x){ return 1.0f - 2.0f/(__expf(2.0f*x)+1.0f); }

__device__ __forceinline__ uint32_t pack2u_(float a, float b){
  h2_t r; r.x=(_Float16)a; r.y=(_Float16)b; return __builtin_bit_cast(uint32_t, r);
}
__device__ __forceinline__ float dot2u_(uint32_t u, uint32_t w, float c){
#if __has_builtin(__builtin_amdgcn_fdot2)
  return __builtin_amdgcn_fdot2(__builtin_bit_cast(h2_t,u), __builtin_bit_cast(h2_t,w), c, false);
#else
  h2_t a=__builtin_bit_cast(h2_t,u), b2=__builtin_bit_cast(h2_t,w);
  return c + (float)a.x*(float)b2.x + (float)a.y*(float)b2.y;
#endif
}
__device__ __forceinline__ float h2f_(unsigned short u){
  _Float16 hv = __builtin_bit_cast(_Float16, u); return (float)hv;
}
__device__ __forceinline__ unsigned short f2h_(float a){
  _Float16 hv = (_Float16)a; return __builtin_bit_cast(unsigned short, hv);
}

// ---------------- fused: stats+x_comp (blocks 0..255)  |  gigru w/ inline x (blocks 256..2303) ----------------
__global__ __launch_bounds__(256) void k_pre(
    const float* __restrict__ values, const float* __restrict__ masks,
    const float* __restrict__ rain_f, const float* __restrict__ rain_b,
    const int* __restrict__ lengths,
    const float* __restrict__ Wih, const float* __restrict__ bih,
    float* __restrict__ x_comp, float* __restrict__ stats,
    unsigned short* __restrict__ gig)
{
  __shared__ float red[4][8][32];
  __shared__ uint32_t WT[48][98];
  __shared__ __align__(16) uint32_t us[16][48];
  const int tid = threadIdx.x;
  if (blockIdx.x < NB){
    // ---------- stats role ----------
    const int b = blockIdx.x;
    const int v = tid & 31;
    const int g = tid >> 5;
    const int len = lengths[b];
    const float* vb = values + (size_t)b*NT*NV;
    const float* mb = masks  + (size_t)b*NT*NV;
    float* xb = x_comp + (size_t)b*NT*NV;
    float s_m=0.f, s_mv=0.f, s_v=0.f, s_v2=0.f;
    for (int t=g; t<NT; t+=8){
      float val = vb[t*NV+v];
      float m   = mb[t*NV+v];
      float xp  = (t==0) ? vb[v] : vb[(t-1)*NV+v];
      float pm  = (t<len) ? 1.0f : 0.0f;
      xb[t*NV+v] = (m*val + (1.0f-m)*xp)*pm;
      s_m += m; s_mv += m*val; s_v += val; s_v2 += val*val;
    }
    red[0][g][v]=s_m; red[1][g][v]=s_mv; red[2][g][v]=s_v; red[3][g][v]=s_v2;
    __syncthreads();
    if (g==0){
      float a0=0,a1=0,a2=0,a3=0;
      #pragma unroll
      for(int i=0;i<8;i++){ a0+=red[0][i][v]; a1+=red[1][i][v]; a2+=red[2][i][v]; a3+=red[3][i][v]; }
      float msum = fmaxf(a0, 1.0f);
      float mean = a1/msum;
      float dss  = a3 - 2.0f*mean*a2 + (float)NT*mean*mean;
      float var  = (msum > 1.0f) ? dss/(msum-1.0f) : 0.0f;
      float sd   = sqrtf(fmaxf(var, 0.0f));
      float miss = 1.0f - a0 / fmaxf((float)len, 1.0f);
      float* st = stats + b*97;
      if (v==0) st[0] = (float)len;
      st[1+v]=mean; st[33+v]=sd; st[65+v]=miss;
    }
    return;
  }
  // ---------- gigru role (x_comp recomputed inline; no dependency on stats role) ----------
  const int bid = blockIdx.x - NB;   // 0..2047
  for (int idx = tid; idx < 48*96; idx += 256){
    const int k = idx / 96, col = idx - k*96;
    WT[k][col] = pack2u_(Wih[(size_t)col*96 + 2*k], Wih[(size_t)col*96 + 2*k + 1]);
  }
  const bool act = (tid < 192);
  const int grp = (tid >= 96) ? 1 : 0;
  const int col = tid - grp*96;
  const float bias = act ? bih[col] : 0.f;
  __syncthreads();
  const int NR = NB*NT;
  for (int r0 = bid*16; r0 < NR; r0 += 2048*16){
    __syncthreads();
    for (int idx = tid; idx < 16*48; idx += 256){
      const int r = idx / 48, w = idx - r*48;
      const size_t row = (size_t)r0 + r;
      const int bb = (int)(row >> 9), t = (int)(row & 511);
      const int len = lengths[bb];
      const float pm = (t < len) ? 1.0f : 0.0f;
      float vz[2];
      #pragma unroll
      for (int z=0; z<2; z++){
        const int i = 2*w + z;
        float a;
        if (i < 32){
          const float val = values[row*32 + i];
          const float m   = masks[row*32 + i];
          const float xp  = (t==0) ? values[((size_t)bb*NT)*32 + i] : values[(row-1)*32 + i];
          a = (m*val + (1.0f-m)*xp)*pm;
        } else if (i < 64){
          a = rain_f[row*32 + i - 32];
        } else {
          a = rain_b[row*32 + i - 64];
        }
        vz[z] = a;
      }
      us[r][w] = pack2u_(vz[0], vz[1]);
    }
    __syncthreads();
    if (act){
      #pragma unroll
      for (int r=0;r<8;r++){
        const int rr = grp*8 + r;
        const uint4* U = (const uint4*)us[rr];
        float acc = bias;
        #pragma unroll
        for (int k4=0;k4<12;k4++){
          const uint4 u4 = U[k4];
          acc = dot2u_(u4.x, WT[4*k4][col],   acc);
          acc = dot2u_(u4.y, WT[4*k4+1][col], acc);
          acc = dot2u_(u4.z, WT[4*k4+2][col], acc);
          acc = dot2u_(u4.w, WT[4*k4+3][col], acc);
        }
        gig[((size_t)r0+rr)*96 + col] = f2h_(acc);
      }
    }
  }
}

// ---------------- fused: GRU scan (blocks 0..255) | context MLP (blocks 256..511), 64 thr ----------------
// GRU role: 4-deep software-pipelined gig prefetch (raw ushort regs, convert at use).
__global__ __launch_bounds__(64,4) void k_gru_cmlp(
    const unsigned short* __restrict__ gig, const int* __restrict__ lengths,
    const float* __restrict__ Whh, const float* __restrict__ bhh,
    const float* __restrict__ stats,
    const float* __restrict__ W1, const float* __restrict__ b1,
    const float* __restrict__ W2, const float* __restrict__ b2,
    float* __restrict__ ctx)
{
  __shared__ __align__(16) _Float16 hbuf[2][32];
  __shared__ float st[97];
  __shared__ float hm[64];
  const int l = threadIdx.x;
  if (blockIdx.x >= NB){
    // ---------- cmlp role ----------
    const int b = blockIdx.x - NB;
    const int j = l;
    for (int k=j; k<97; k+=64) st[k] = stats[b*97+k];
    __syncthreads();
    float a0=b1[j], a1=0.f, a2=0.f, a3=0.f;
    #pragma unroll
    for (int k=0; k<96; k+=4){
      a0 += st[k]*W1[j*97+k];     a1 += st[k+1]*W1[j*97+k+1];
      a2 += st[k+2]*W1[j*97+k+2]; a3 += st[k+3]*W1[j*97+k+3];
    }
    a0 += st[96]*W1[j*97+96];
    hm[j] = fmaxf((a0+a1)+(a2+a3), 0.0f);
    __syncthreads();
    if (j < 32){
      float c0_=b2[j], c1=0.f, c2=0.f, c3=0.f;
      #pragma unroll
      for (int k=0;k<64;k+=4){
        c0_ += hm[k]*W2[j*64+k];    c1 += hm[k+1]*W2[j*64+k+1];
        c2 += hm[k+2]*W2[j*64+k+2]; c3 += hm[k+3]*W2[j*64+k+3];
      }
      ctx[b*64+j] = (c0_+c1)+(c2+c3);
    }
    return;
  }
  // ---------- gru role (4-deep pipelined) ----------
  const int b = blockIdx.x;
  const int arow = l & 15, ak = (l >> 4) * 8;
  const int rg = l >> 4, j4 = l & 3;
  const int crow = rg * 4;
  const int e0 = crow + j4, e1 = 16 + e0;
  const bool writer = ((l & 15) >> 2) == 0;
  f16x8 A0, A1, A2, A3, A4, A5;
  #define LDA(dst, mt) { const float* p_ = Whh + (size_t)((mt)*16 + arow)*32 + ak; \
    f16x8 t_; _Pragma("unroll") for (int e_=0;e_<8;++e_) t_[e_] = (_Float16)p_[e_]; dst = t_; }
  LDA(A0,0) LDA(A1,1) LDA(A2,2) LDA(A3,3) LDA(A4,4) LDA(A5,5)
  #undef LDA
  f32x4 bb0, bb1, bb2, bb3, bb4, bb5;
  #pragma unroll
  for (int j=0;j<4;j++){
    bb0[j] = bhh[0*16 + crow + j]; bb1[j] = bhh[1*16 + crow + j];
    bb2[j] = bhh[2*16 + crow + j]; bb3[j] = bhh[3*16 + crow + j];
    bb4[j] = bhh[4*16 + crow + j]; bb5[j] = bhh[5*16 + crow + j];
  }
  asm volatile("" ::: "memory");
  int len = lengths[b]; if (len > NT) len = NT;
  float h0v = 0.f, h1v = 0.f;
  if (l < 32) hbuf[0][l] = (_Float16)0.f;
  const unsigned short* gp = gig + (size_t)b*NT*96;
  unsigned short uA0=0,uA1=0,uA2=0,uA3=0,uA4=0,uA5=0;
  unsigned short uB0=0,uB1=0,uB2=0,uB3=0,uB4=0,uB5=0;
  unsigned short uC0=0,uC1=0,uC2=0,uC3=0,uC4=0,uC5=0;
  unsigned short uD0=0,uD1=0,uD2=0,uD3=0,uD4=0,uD5=0;
  #define PF(tq, U0,U1,U2,U3,U4,U5) { const int tq_ = (tq); \
    if (tq_ < len){ const unsigned short* gq_ = gp + (size_t)tq_*96; \
      U0 = gq_[e0]; U1 = gq_[32+e0]; U2 = gq_[64+e0]; \
      U3 = gq_[e1]; U4 = gq_[32+e1]; U5 = gq_[64+e1]; } }
  PF(0, uA0,uA1,uA2,uA3,uA4,uA5)
  PF(1, uB0,uB1,uB2,uB3,uB4,uB5)
  PF(2, uC0,uC1,uC2,uC3,uC4,uC5)
  PF(3, uD0,uD1,uD2,uD3,uD4,uD5)
  __syncthreads();
  #define STEP(tt, U0,U1,U2,U3,U4,U5) { const int t_ = (tt); \
    if (t_ < len){ \
      const int cur_ = t_ & 1; \
      const f16x8 bh_ = *(const f16x8*)&hbuf[cur_][ak]; \
      f32x4 a0 = bb0, a1 = bb1, a2 = bb2, a3 = bb3, a4 = bb4, a5 = bb5; \
      a0 = __builtin_amdgcn_mfma_f32_16x16x32_f16(A0, bh_, a0, 0, 0, 0); \
      a1 = __builtin_amdgcn_mfma_f32_16x16x32_f16(A1, bh_, a1, 0, 0, 0); \
      a2 = __builtin_amdgcn_mfma_f32_16x16x32_f16(A2, bh_, a2, 0, 0, 0); \
      a3 = __builtin_amdgcn_mfma_f32_16x16x32_f16(A3, bh_, a3, 0, 0, 0); \
      a4 = __builtin_amdgcn_mfma_f32_16x16x32_f16(A4, bh_, a4, 0, 0, 0); \
      a5 = __builtin_amdgcn_mfma_f32_16x16x32_f16(A5, bh_, a5, 0, 0, 0); \
      const float r0_ = sigmoidf_(h2f_(U0) + a0[j4]); \
      const float z0_ = sigmoidf_(h2f_(U1) + a2[j4]); \
      const float n0_ = tanhf_(h2f_(U2) + r0_*a4[j4]); \
      h0v = (1.0f - z0_)*n0_ + z0_*h0v; \
      const float r1_ = sigmoidf_(h2f_(U3) + a1[j4]); \
      const float z1_ = sigmoidf_(h2f_(U4) + a3[j4]); \
      const float n1_ = tanhf_(h2f_(U5) + r1_*a5[j4]); \
      h1v = (1.0f - z1_)*n1_ + z1_*h1v; \
      if (writer){ \
        hbuf[cur_^1][e0] = (_Float16)h0v; \
        hbuf[cur_^1][e1] = (_Float16)h1v; \
      } \
      __syncthreads(); } }
  for (int t=0; t<len; t+=4){
    STEP(t,   uA0,uA1,uA2,uA3,uA4,uA5)  PF(t+4, uA0,uA1,uA2,uA3,uA4,uA5)
    STEP(t+1, uB0,uB1,uB2,uB3,uB4,uB5)  PF(t+5, uB0,uB1,uB2,uB3,uB4,uB5)
    STEP(t+2, uC0,uC1,uC2,uC3,uC4,uC5)  PF(t+6, uC0,uC1,uC2,uC3,uC4,uC5)
    STEP(t+3, uD0,uD1,uD2,uD3,uD4,uD5)  PF(t+7, uD0,uD1,uD2,uD3,uD4,uD5)
  }
  #undef STEP
  #undef PF
  if (writer){
    ctx[b*64 + 32 + e0] = h0v;
    ctx[b*64 + 32 + e1] = h1v;
  }
}

// ---------------- fused LSTM scan (+in-block init) + feature-regression ----------------
// grid (256, 3), 256 thr, launch_bounds(256,2). LSTM plane computes its own cg/h0/c0 from ctx
// (k_init folded in); hidb stride 40 f16 (r20-proven).
__global__ __launch_bounds__(256,2) void k_lstm_feat(
    const float* __restrict__ x_comp, const float* __restrict__ masks,
    const float* __restrict__ WihF, const float* __restrict__ WhhF,
    const float* __restrict__ WihB, const float* __restrict__ WhhB,
    const float* __restrict__ bihF, const float* __restrict__ bhhF,
    const float* __restrict__ bihB, const float* __restrict__ bhhB,
    const float* __restrict__ initW, const float* __restrict__ initb,
    const float* __restrict__ ctx,
    const int* __restrict__ lengths,
    float* __restrict__ hidden,
    const float* __restrict__ feat_W, const float* __restrict__ feat_b,
    const float* __restrict__ nl1_W, const float* __restrict__ nl1_b,
    const float* __restrict__ nl2_W, const float* __restrict__ nl2_b,
    float* __restrict__ feat_imp)
{
  __shared__ __align__(16) _Float16 ubuf[2][64];
  __shared__ __align__(16) _Float16 hbuf[2][64];
  __shared__ __align__(16) _Float16 xbuf[16*32];
  __shared__ __align__(16) _Float16 hidb[32*16*40];     // stride 40 (padded)
  __shared__ __align__(16) float fbl[1024];
  __shared__ float fout[16*33];
  __shared__ __align__(16) float cvl[64];
  __shared__ float cgl[256];
  __shared__ float c0l[64];
  const int tid = threadIdx.x;
  if (blockIdx.y < 2){
    // ================= LSTM path (r17 body + fused init prologue) =================
    const int b = blockIdx.x, dir = blockIdx.y;
    const int l = tid & 63, wv = tid >> 6;
    const int eg = wv * 16;
    const int arow = l & 15, ak = (l >> 4) * 8;
    const int rowg = l >> 4;
    const int j4 = l & 3;
    const int elem = eg + rowg*4 + j4;
    const bool writer = ((l & 15) >> 2) == 0;
    const float* Wih = dir ? WihB : WihF;
    const float* Whh = dir ? WhhB : WhhF;
    const float* bih = dir ? bihB : bihF;
    const float* bhh = dir ? bhhB : bhhF;
    // --- init prologue: cg rows, h0/c0 for this dir, seed row of hidden ---
    if (tid < 64) cvl[tid] = ctx[(size_t)b*64 + tid];
    __syncthreads();
    {
      const int j = tid;
      float acc = bih[j] + bhh[j];
      const float* wr = Wih + (size_t)j*128 + 64;
      #pragma unroll
      for (int k=0;k<64;k+=4){
        const float4 cv4 = *(const float4*)&cvl[k];
        const float4 w4  = *(const float4*)&wr[k];
        acc += cv4.x*w4.x + cv4.y*w4.y + cv4.z*w4.z + cv4.w*w4.w;
      }
      cgl[j] = acc;
    }
    if (tid < 64){
      const int j = dir*64 + tid;
      float acc = initb[j];
      const float* wr = initW + (size_t)j*64;
      #pragma unroll
      for (int k=0;k<64;k+=4){
        const float4 cv4 = *(const float4*)&cvl[k];
        const float4 w4  = *(const float4*)&wr[k];
        acc += cv4.x*w4.x + cv4.y*w4.y + cv4.z*w4.z + cv4.w*w4.w;
      }
      hbuf[0][tid] = (_Float16)acc;
      c0l[tid] = tanhf_(acc);
      const int ts = dir ? NT-1 : 0;
      hidden[(size_t)b*NT*128 + (size_t)ts*128 + dir*64 + tid] = acc;
    }
    // --- weight fragments (independent global loads) ---
    f16x8 X0a,X0b,X1a,X1b,X2a,X2b,X3a,X3b;
    f16x8 H0a,H0b,H1a,H1b,H2a,H2b,H3a,H3b;
    #define LDFRAG(dst, base, ld, row, kk) { \
      const float* p_ = (base) + (size_t)(row)*(ld) + (kk); \
      const float4 v0_ = *(const float4*)p_; const float4 v1_ = *(const float4*)(p_+4); \
      f16x8 t_; t_[0]=(_Float16)v0_.x; t_[1]=(_Float16)v0_.y; t_[2]=(_Float16)v0_.z; t_[3]=(_Float16)v0_.w; \
      t_[4]=(_Float16)v1_.x; t_[5]=(_Float16)v1_.y; t_[6]=(_Float16)v1_.z; t_[7]=(_Float16)v1_.w; dst = t_; }
    LDFRAG(X0a, Wih, 128, 0*64+eg+arow, ak)    LDFRAG(X0b, Wih, 128, 0*64+eg+arow, 32+ak)
    LDFRAG(X1a, Wih, 128, 1*64+eg+arow, ak)    LDFRAG(X1b, Wih, 128, 1*64+eg+arow, 32+ak)
    LDFRAG(X2a, Wih, 128, 2*64+eg+arow, ak)    LDFRAG(X2b, Wih, 128, 2*64+eg+arow, 32+ak)
    LDFRAG(X3a, Wih, 128, 3*64+eg+arow, ak)    LDFRAG(X3b, Wih, 128, 3*64+eg+arow, 32+ak)
    LDFRAG(H0a, Whh, 64,  0*64+eg+arow, ak)    LDFRAG(H0b, Whh, 64,  0*64+eg+arow, 32+ak)
    LDFRAG(H1a, Whh, 64,  1*64+eg+arow, ak)    LDFRAG(H1b, Whh, 64,  1*64+eg+arow, 32+ak)
    LDFRAG(H2a, Whh, 64,  2*64+eg+arow, ak)    LDFRAG(H2b, Whh, 64,  2*64+eg+arow, 32+ak)
    LDFRAG(H3a, Whh, 64,  3*64+eg+arow, ak)    LDFRAG(H3b, Whh, 64,  3*64+eg+arow, 32+ak)
    #undef LDFRAG
    const int len = lengths[b];
    int nsteps = NT-1;
    if (dir == 0){ int e = len-1; if (e<0) e=0; if (e<nsteps) nsteps = e; }
    const float* xc = x_comp + (size_t)b*NT*NV;
    const float* mk = masks  + (size_t)b*NT*NV;
    float* hout = hidden + (size_t)b*NT*128 + dir*64;
    if (tid >= 64 && tid < 96 && nsteps > 0){
      const int u = tid - 64;
      const int t0 = dir ? NT-1 : 0;
      const float2 v = (u<16) ? *(const float2*)(xc + t0*NV + 2*u)
                              : *(const float2*)(mk + t0*NV + 2*(u-16));
      ubuf[0][2*u] = (_Float16)v.x; ubuf[0][2*u+1] = (_Float16)v.y;
    }
    __syncthreads();   // cgl/c0l/hbuf[0]/ubuf[0] ready
    const int crow = rowg * 4;
    f32x4 cgi, cgf, cgg, cgo;
    #pragma unroll
    for (int j=0;j<4;j++){
      cgi[j] = cgl[0*64 + eg + crow + j];
      cgf[j] = cgl[1*64 + eg + crow + j];
      cgg[j] = cgl[2*64 + eg + crow + j];
      cgo[j] = cgl[3*64 + eg + crow + j];
    }
    float cst = c0l[elem];
    asm volatile("" ::: "memory");
    for (int s=0; s<nsteps; ++s){
      const int cur = s & 1;
      float2 pre = {0.f, 0.f};
      const bool dopf = (tid >= 64 && tid < 96 && s+1 < nsteps);
      if (dopf){
        const int u = tid - 64;
        const int tn = dir ? (NT-2-s) : (s+1);
        pre = (u<16) ? *(const float2*)(xc + tn*NV + 2*u)
                     : *(const float2*)(mk + tn*NV + 2*(u-16));
      }
      const f16x8 bu0 = *(const f16x8*)&ubuf[cur][ak];
      const f16x8 bu1 = *(const f16x8*)&ubuf[cur][32+ak];
      const f16x8 bh0 = *(const f16x8*)&hbuf[cur][ak];
      const f16x8 bh1 = *(const f16x8*)&hbuf[cur][32+ak];
      f32x4 ai = cgi, af = cgf, ag = cgg, ao = cgo;
      ai = __builtin_amdgcn_mfma_f32_16x16x32_f16(X0a, bu0, ai, 0, 0, 0);
      af = __builtin_amdgcn_mfma_f32_16x16x32_f16(X1a, bu0, af, 0, 0, 0);
      ag = __builtin_amdgcn_mfma_f32_16x16x32_f16(X2a, bu0, ag, 0, 0, 0);
      ao = __builtin_amdgcn_mfma_f32_16x16x32_f16(X3a, bu0, ao, 0, 0, 0);
      ai = __builtin_amdgcn_mfma_f32_16x16x32_f16(X0b, bu1, ai, 0, 0, 0);
      af = __builtin_amdgcn_mfma_f32_16x16x32_f16(X1b, bu1, af, 0, 0, 0);
      ag = __builtin_amdgcn_mfma_f32_16x16x32_f16(X2b, bu1, ag, 0, 0, 0);
      ao = __builtin_amdgcn_mfma_f32_16x16x32_f16(X3b, bu1, ao, 0, 0, 0);
      ai = __builtin_amdgcn_mfma_f32_16x16x32_f16(H0a, bh0, ai, 0, 0, 0);
      af = __builtin_amdgcn_mfma_f32_16x16x32_f16(H1a, bh0, af, 0, 0, 0);
      ag = __builtin_amdgcn_mfma_f32_16x16x32_f16(H2a, bh0, ag, 0, 0, 0);
      ao = __builtin_amdgcn_mfma_f32_16x16x32_f16(H3a, bh0, ao, 0, 0, 0);
      ai = __builtin_amdgcn_mfma_f32_16x16x32_f16(H0b, bh1, ai, 0, 0, 0);
      af = __builtin_amdgcn_mfma_f32_16x16x32_f16(H1b, bh1, af, 0, 0, 0);
      ag = __builtin_amdgcn_mfma_f32_16x16x32_f16(H2b, bh1, ag, 0, 0, 0);
      ao = __builtin_amdgcn_mfma_f32_16x16x32_f16(H3b, bh1, ao, 0, 0, 0);
      const float gi = ai[j4], gf = af[j4], gg = ag[j4], go = ao[j4];
      cst = sigmoidf_(gf)*cst + sigmoidf_(gi)*tanhf_(gg);
      const float hh = sigmoidf_(go)*tanhf_(cst);
      if (writer){
        hbuf[cur^1][elem] = (_Float16)hh;
        const int outt = dir ? (NT-2-s) : (s+1);
        hout[(size_t)outt*128 + elem] = hh;
      }
      if (dopf){
        const int u = tid - 64;
        ubuf[cur^1][2*u]   = (_Float16)pre.x;
        ubuf[cur^1][2*u+1] = (_Float16)pre.y;
      }
      __syncthreads();
    }
    return;
  }
  // ================= feat path (4 waves, padded hidb) =================
  {
    const int l = tid & 63, wv = tid >> 6;         // wv 0..3
    const int fr = l >> 4, fc = l & 15;
    const int ak = fr * 8;
    f16x8 WA[16];
    #pragma unroll
    for (int q=0;q<16;q++){
      const int m_ = (wv*16 + q)*16 + fc;
      const int i_ = m_ >> 5;
      const float* s_ = feat_W + (size_t)m_*32 + ak;
      f16x8 t_;
      #pragma unroll
      for (int e_=0; e_<8; ++e_){
        float w_ = s_[e_];
        if (ak + e_ == i_) w_ = 0.f;
        t_[e_] = (_Float16)w_;
      }
      WA[q] = t_;
    }
    f16x8 NA0, NA1;
    {
      f16x8 t0, t1;
      #pragma unroll
      for (int e=0;e<8;e++){
        t0[e] = (_Float16)nl1_W[(fc)*32 + ak + e];
        t1[e] = (_Float16)nl1_W[(16 + fc)*32 + ak + e];
      }
      NA0 = t0; NA1 = t1;
    }
    f32x4 n1b0, n1b1;
    float n2w0[4], n2w1[4];
    #pragma unroll
    for (int j=0;j<4;j++){
      n1b0[j] = nl1_b[fr*4+j];
      n1b1[j] = nl1_b[16 + fr*4+j];
      n2w0[j] = nl2_W[fr*4+j];
      n2w1[j] = nl2_W[16 + fr*4+j];
    }
    const float n2b = nl2_b[0];
    for (int idx = tid; idx < 1024; idx += 256) fbl[idx] = feat_b[idx];
    asm volatile("" ::: "memory");
    const int NG = (NB*NT)/16;
    for (int g = blockIdx.x; g < NG; g += 256){
      const size_t r0 = (size_t)g*16;
      __syncthreads();
      {
        const int n0 = tid >> 4, v2 = (tid & 15)*2;   // 2 elems/thread
        const float2 xv = *(const float2*)&x_comp[(r0+n0)*32 + v2];
        xbuf[n0*32+v2]   = (_Float16)xv.x;
        xbuf[n0*32+v2+1] = (_Float16)xv.y;
      }
      __syncthreads();
      const f16x8 xB = *(const f16x8*)&xbuf[fc*32 + ak];
      #pragma unroll
      for (int q=0;q<16;q++){
        const int mt = wv*16 + q;
        f32x4 acc = {0.f,0.f,0.f,0.f};
        acc = __builtin_amdgcn_mfma_f32_16x16x32_f16(WA[q], xB, acc, 0, 0, 0);
        const int mbase = mt*16 + fr*4;
        const f32x4 fb4 = *(const f32x4*)&fbl[mbase];
        #pragma unroll
        for (int jj=0;jj<4;jj+=2){
          const int m0_ = mbase + jj;
          const int i_ = m0_ >> 5, h_ = m0_ & 31;
          const float v0_ = fmaxf(acc[jj]   + fb4[jj],   0.f);
          const float v1_ = fmaxf(acc[jj+1] + fb4[jj+1], 0.f);
          h2_t p; p.x = (_Float16)v0_; p.y = (_Float16)v1_;
          *(h2_t*)&hidb[(i_*16+fc)*40 + h_] = p;
        }
      }
      __syncthreads();
      float outv[8];
      #pragma unroll
      for (int q=0;q<8;q++){
        const int nt = wv*8 + q;
        const f16x8 hB = *(const f16x8*)&hidb[(nt*16+fc)*40 + ak];
        f32x4 z0 = n1b0, z1 = n1b1;
        z0 = __builtin_amdgcn_mfma_f32_16x16x32_f16(NA0, hB, z0, 0, 0, 0);
        z1 = __builtin_amdgcn_mfma_f32_16x16x32_f16(NA1, hB, z1, 0, 0, 0);
        float s = 0.f;
        #pragma unroll
        for (int j=0;j<4;j++){
          s += fmaxf(z0[j], 0.f)*n2w0[j];
          s += fmaxf(z1[j], 0.f)*n2w1[j];
        }
        s += __shfl_xor(s, 16);
        s += __shfl_xor(s, 32);
        outv[q] = s;
      }
      if (fr == 0){
        #pragma unroll
        for (int q=0;q<8;q++) fout[fc*33 + wv*8 + q] = outv[q] + n2b;
      }
      __syncthreads();
      feat_imp[r0*32 + tid]       = fout[(tid>>5)*33 + (tid&31)];
      feat_imp[r0*32 + 256 + tid] = fout[((tid+256)>>5)*33 + (tid&31)];
    }
  }
}

// ---------------- rnn_imp GEMM + fuse + final: LDS f16 rimp ----------------
__global__ __launch_bounds__(512) void k_final(
    const float* __restrict__ values, const float* __restrict__ masks,
    const float* __restrict__ feat_imp, const float* __restrict__ hidden,
    const float* __restrict__ rimp_W, const float* __restrict__ rimp_b,
    const float* __restrict__ fuse_W, const float* __restrict__ fuse_b,
    const int* __restrict__ lengths, float* __restrict__ out)
{
  const int tid = threadIdx.x;
  const int v = tid & 31;
  const int grp = (tid >> 5) & 7;
  const int half = tid >> 8;
  __shared__ uint32_t rpT[64][32];
  __shared__ __align__(16) uint32_t hrowp[8][64];
  __shared__ float rpart[8][32];
  __shared__ float bpart[8][32];
  for (int idx = tid; idx < 64*32; idx += 512){
    const int k = idx >> 5, vv = idx & 31;
    rpT[k][vv] = pack2u_(rimp_W[(size_t)vv*128 + 2*k], rimp_W[(size_t)vv*128 + 2*k+1]);
  }
  const float4* F4 = (const float4*)(fuse_W + (size_t)v*64 + 32);
  float fconst = 0.f;
  if (!half){
    fconst = fuse_b[v];
    #pragma unroll
    for (int q=0;q<8;q++){
      const float4 fw = *(const float4*)(fuse_W + (size_t)v*64 + 4*q);
      fconst += (fw.x+fw.y)+(fw.z+fw.w);
    }
  }
  const float rbias = rimp_b[v];
  __syncthreads();
  const int NOCT = (NB*NT)/8;
  for (int oc = blockIdx.x; oc < NOCT; oc += gridDim.x){
    const size_t base = (size_t)oc*8;
    __syncthreads();
    if (tid < 256){
      const float4 hv = ((const float4*)(hidden + base*128))[tid];
      const int row = tid >> 5;
      const int w0 = (tid & 31) << 1;
      hrowp[row][w0]   = pack2u_(hv.x, hv.y);
      hrowp[row][w0+1] = pack2u_(hv.z, hv.w);
    }
    __syncthreads();
    const size_t r = base + grp;
    float a = half ? 0.f : rbias;
    {
      const uint4* hp4 = (const uint4*)&hrowp[grp][half*32];
      #pragma unroll
      for (int c4=0;c4<8;c4++){
        const uint4 H = hp4[c4];
        a = dot2u_(H.x, rpT[half*32 + 4*c4][v],     a);
        a = dot2u_(H.y, rpT[half*32 + 4*c4 + 1][v], a);
        a = dot2u_(H.z, rpT[half*32 + 4*c4 + 2][v], a);
        a = dot2u_(H.w, rpT[half*32 + 4*c4 + 3][v], a);
      }
    }
    if (half){
      rpart[grp][v] = a;
      const float* mrow = masks + r*32;
      float m0=0,m1=0,m2=0,m3=0;
      #pragma unroll
      for (int q=0;q<8;q++){
        const float4 mv = *(const float4*)(mrow + 4*q);
        const float4 fv = F4[q];
        m0 = fmaf(mv.x, fv.x, m0); m1 = fmaf(mv.y, fv.y, m1);
        m2 = fmaf(mv.z, fv.z, m2); m3 = fmaf(mv.w, fv.w, m3);
      }
      bpart[grp][v] = (m0+m1)+(m2+m3);
    }
    __syncthreads();
    if (!half){
      const int bb = (int)(r >> 9);
      const int t  = (int)(r & 511);
      const int len = lengths[bb];
      const float rimp = a + rpart[grp][v];
      const float beta = sigmoidf_(fconst + bpart[grp][v]);
      const float fi = feat_imp[r*32+v];
      const float m  = masks[r*32+v];
      const float val= values[r*32+v];
      const float fz = beta*fi + (1.0f-beta)*rimp;
      const float o = m*val + (1.0f-m)*fz;
      out[r*32+v] = (t < len) ? o : 0.0f;
    }
  }
}

extern "C" void kernel_launch(void* const* d_in, const int* in_sizes, int n_in,
                              void* d_out, int out_size, void* d_ws, size_t ws_size,
                              hipStream_t stream) {
  const float* values   = (const float*)d_in[0];
  const float* masks    = (const float*)d_in[1];
  const float* rain_f   = (const float*)d_in[2];
  const float* rain_b   = (const float*)d_in[3];
  const float* cmlp_W1  = (const float*)d_in[4];
  const float* cmlp_b1  = (const float*)d_in[5];
  const float* cmlp_W2  = (const float*)d_in[6];
  const float* cmlp_b2  = (const float*)d_in[7];
  const float* gru_Wih  = (const float*)d_in[8];
  const float* gru_Whh  = (const float*)d_in[9];
  const float* gru_bih  = (const float*)d_in[10];
  const float* gru_bhh  = (const float*)d_in[11];
  const float* init_W   = (const float*)d_in[12];
  const float* init_b   = (const float*)d_in[13];
  const float* lstmf_Wih= (const float*)d_in[14];
  const float* lstmf_Whh= (const float*)d_in[15];
  const float* lstmf_bih= (const float*)d_in[16];
  const float* lstmf_bhh= (const float*)d_in[17];
  const float* lstmb_Wih= (const float*)d_in[18];
  const float* lstmb_Whh= (const float*)d_in[19];
  const float* lstmb_bih= (const float*)d_in[20];
  const float* lstmb_bhh= (const float*)d_in[21];
  const float* rimp_W   = (const float*)d_in[22];
  const float* rimp_b   = (const float*)d_in[23];
  const float* feat_W   = (const float*)d_in[24];
  const float* feat_b   = (const float*)d_in[25];
  const float* nl1_W    = (const float*)d_in[26];
  const float* nl1_b    = (const float*)d_in[27];
  const float* nl2_W    = (const float*)d_in[28];
  const float* nl2_b    = (const float*)d_in[29];
  const float* fuse_W   = (const float*)d_in[30];
  const float* fuse_b   = (const float*)d_in[31];
  const int*   lengths  = (const int*)d_in[32];
  float* out = (float*)d_out;

  float* ws       = (float*)d_ws;
  float* x_comp   = ws;                                   // B*T*V
  float* stats    = x_comp + (size_t)NB*NT*NV;            // B*97
  float* ctx      = stats + NB*97;                        // B*64
  float* h0       = ctx + NB*64;                          // B*128 (unused)
  float* c0      = h0 + NB*128;                           // B*128 (unused)
  float* cgF      = c0 + NB*128;                          // B*256 (unused)
  float* cgB      = cgF + NB*256;                         // B*256 (unused)
  float* hidden   = cgB + NB*256;                         // B*T*128
  float* feat_imp = hidden + (size_t)NB*NT*128;           // B*T*V
  unsigned short* gig = (unsigned short*)(feat_imp + (size_t)NB*NT*NV); // B*T*96 f16
  // total ~127 MB

  k_pre<<<NB + 2048, 256, 0, stream>>>(values, masks, rain_f, rain_b, lengths,
                                       gru_Wih, gru_bih, x_comp, stats, gig);
  k_gru_cmlp<<<2*NB, 64, 0, stream>>>(gig, lengths, gru_Whh, gru_bhh,
                                      stats, cmlp_W1, cmlp_b1, cmlp_W2, cmlp_b2, ctx);
  dim3 lgrid(NB, 3);
  k_lstm_feat<<<lgrid, 256, 0, stream>>>(x_comp, masks,
                                         lstmf_Wih, lstmf_Whh, lstmb_Wih, lstmb_Whh,
                                         lstmf_bih, lstmf_bhh, lstmb_bih, lstmb_bhh,
                                         init_W, init_b, ctx, lengths, hidden,
                                         feat_W, feat_b, nl1_W, nl1_b, nl2_W, nl2_b, feat_imp);
  k_final<<<2048, 512, 0, stream>>>(values, masks, feat_imp, hidden,
                                    rimp_W, rimp_b, fuse_W, fuse_b, lengths, out);
}